// Round 1
// baseline (593.195 us; speedup 1.0000x reference)
//
#include <hip/hip_runtime.h>
#include <stdint.h>

#define NTOK 8192
#define CAP  1280
#define NEXP 32

typedef __bf16 bf16x8 __attribute__((ext_vector_type(8)));
typedef float f32x4 __attribute__((ext_vector_type(4)));
typedef unsigned short u16;

__device__ __forceinline__ u16 f2bf(float f) {
  unsigned u = __builtin_bit_cast(unsigned, f);
  u = (u + 0x7fffu + ((u >> 16) & 1u)) >> 16;
  return (u16)u;
}
__device__ __forceinline__ float bf2f(u16 h) {
  return __builtin_bit_cast(float, ((unsigned)h) << 16);
}

__device__ __forceinline__ void gload16(const void* g, void* l) {
  __builtin_amdgcn_global_load_lds(
      (const __attribute__((address_space(1))) void*)g,
      (__attribute__((address_space(3))) void*)l, 16, 0, 0);
}

// ---------------- convert x (fp32 -> bf16), 4 elems/thread ----------------
__global__ __launch_bounds__(256) void conv_x_kernel(const float* __restrict__ in,
                                                     u16* __restrict__ out) {
  int i = blockIdx.x * 256 + threadIdx.x;
  float4 v = reinterpret_cast<const float4*>(in)[i];
  uint2 o;
  o.x = (unsigned)f2bf(v.x) | ((unsigned)f2bf(v.y) << 16);
  o.y = (unsigned)f2bf(v.z) | ((unsigned)f2bf(v.w) << 16);
  reinterpret_cast<uint2*>(out)[i] = o;
}

// -------- transpose+convert 1024x1024 fp32 -> bf16, all weights in one ----
__global__ __launch_bounds__(256) void tconv_all_kernel(
    const float* __restrict__ w1, const float* __restrict__ w3,
    const float* __restrict__ w2, const float* __restrict__ sw1,
    const float* __restrict__ sw3, const float* __restrict__ sw2,
    u16* __restrict__ w1t, u16* __restrict__ w3t, u16* __restrict__ w2t,
    u16* __restrict__ sw1t, u16* __restrict__ sw3t, u16* __restrict__ sw2t) {
  __shared__ float tile[32][33];
  const int z = blockIdx.z;
  const float* src;
  u16* dst;
  if (z < 32)      { src = w1 + (size_t)z * 1048576;        dst = w1t + (size_t)z * 1048576; }
  else if (z < 64) { src = w3 + (size_t)(z - 32) * 1048576; dst = w3t + (size_t)(z - 32) * 1048576; }
  else if (z < 96) { src = w2 + (size_t)(z - 64) * 1048576; dst = w2t + (size_t)(z - 64) * 1048576; }
  else if (z == 96){ src = sw1; dst = sw1t; }
  else if (z == 97){ src = sw3; dst = sw3t; }
  else             { src = sw2; dst = sw2t; }
  int r0 = blockIdx.x * 32, c0 = blockIdx.y * 32;
  int tid = threadIdx.x;
#pragma unroll
  for (int i = 0; i < 4; ++i) {
    int t = tid + i * 256, r = t >> 5, c = t & 31;
    tile[r][c] = src[(size_t)(r0 + r) * 1024 + (c0 + c)];
  }
  __syncthreads();
#pragma unroll
  for (int i = 0; i < 4; ++i) {
    int t = tid + i * 256, cc = t >> 5, rr = t & 31;
    dst[(size_t)(c0 + cc) * 1024 + (r0 + rr)] = f2bf(tile[rr][cc]);
  }
}

// ---------------- gating: one block per token ----------------
__global__ __launch_bounds__(256) void gate_kernel(const float* __restrict__ x,
                                                   const float* __restrict__ wg,
                                                   int* __restrict__ gidx,
                                                   float* __restrict__ gw) {
  const int t = blockIdx.x;
  __shared__ float xl[1024];
  __shared__ float logits[32];
  const int tid = threadIdx.x;
  reinterpret_cast<float4*>(xl)[tid] = reinterpret_cast<const float4*>(x + (size_t)t * 1024)[tid];
  __syncthreads();
  const int e = tid >> 3, p = tid & 7;
  const float4* wrow = reinterpret_cast<const float4*>(wg + (size_t)e * 1024);
  const float4* xv4 = reinterpret_cast<const float4*>(xl);
  float s = 0.f;
#pragma unroll
  for (int i = 0; i < 32; ++i) {
    int c = p + 8 * i;
    float4 xv = xv4[c];
    float4 wv = wrow[c];
    s += xv.x * wv.x + xv.y * wv.y + xv.z * wv.z + xv.w * wv.w;
  }
  s += __shfl_xor(s, 1);
  s += __shfl_xor(s, 2);
  s += __shfl_xor(s, 4);
  if (p == 0) logits[e] = s;
  __syncthreads();
  if (tid == 0) {
    float m = logits[0];
#pragma unroll
    for (int i = 1; i < 32; ++i) m = fmaxf(m, logits[i]);
    float sum = 0.f;
#pragma unroll
    for (int i = 0; i < 32; ++i) sum += expf(logits[i] - m);
    float gm[8];
#pragma unroll
    for (int g = 0; g < 8; ++g) {
      float v = logits[4 * g];
      v = fmaxf(v, logits[4 * g + 1]);
      v = fmaxf(v, logits[4 * g + 2]);
      v = fmaxf(v, logits[4 * g + 3]);
      gm[g] = v;
    }
    unsigned gkeep = 0;
    for (int it = 0; it < 4; ++it) {
      float best = -3.4e38f; int bg = 0;
#pragma unroll
      for (int g = 0; g < 8; ++g) {
        bool ok = !((gkeep >> g) & 1u);
        if (ok && gm[g] > best) { best = gm[g]; bg = g; }
      }
      gkeep |= 1u << bg;
    }
    unsigned allow = 0;
#pragma unroll
    for (int g = 0; g < 8; ++g)
      if ((gkeep >> g) & 1u) allow |= 0xFu << (4 * g);
    unsigned taken = 0;
    float wsum = 0.f;
    int ids[4]; float wv[4];
    for (int sIt = 0; sIt < 4; ++sIt) {
      float best = -3.4e38f; int be = 0;
#pragma unroll
      for (int i = 0; i < 32; ++i) {
        bool ok = ((allow >> i) & 1u) && !((taken >> i) & 1u);
        float v = logits[i];
        if (ok && v > best) { best = v; be = i; }
      }
      taken |= 1u << be;
      ids[sIt] = be;
      float wq = expf(logits[be] - m) / sum;
      wv[sIt] = wq;
      wsum += wq;
    }
    float inv = 1.f / (wsum + 1e-9f);
#pragma unroll
    for (int sIt = 0; sIt < 4; ++sIt) {
      gidx[t * 4 + sIt] = ids[sIt];
      gw[t * 4 + sIt] = wv[sIt] * inv;
    }
  }
}

// ---------------- init dispatch buffers ----------------
__global__ __launch_bounds__(256) void initbuf_kernel(int* __restrict__ bt, float* __restrict__ bw) {
  int i = blockIdx.x * 256 + threadIdx.x;
  if (i < NEXP * CAP) { bt[i] = -1; bw[i] = 0.f; }
}

// ---------------- rank/dispatch: one block per expert, 1024 threads --------
__global__ __launch_bounds__(1024) void rank_kernel(const int* __restrict__ gidx,
                                                    const float* __restrict__ gw,
                                                    int* __restrict__ buf_tok,
                                                    float* __restrict__ buf_w,
                                                    int* __restrict__ cnt,
                                                    int* __restrict__ tslot) {
  const int e = blockIdx.x;
  const int tid = threadIdx.x, wid = tid >> 6, lane = tid & 63;
  __shared__ int wtot[16];
  int base = 0;
  for (int j0 = 0; j0 < NTOK * 4; j0 += 1024) {
    int j = j0 + tid;
    bool match = (gidx[j] == e);
    unsigned long long mb = __ballot(match);
    if (lane == 0) wtot[wid] = __popcll(mb);
    __syncthreads();
    int woff = 0, btot = 0;
#pragma unroll
    for (int w = 0; w < 16; ++w) {
      int c = wtot[w];
      if (w < wid) woff += c;
      btot += c;
    }
    if (match) {
      int pos = base + woff + __popcll(mb & ((1ull << lane) - 1ull));
      if (pos < CAP) {
        buf_tok[e * CAP + pos] = j >> 2;
        buf_w[e * CAP + pos] = gw[j];
        tslot[j] = e * CAP + pos;
      } else {
        tslot[j] = -1;
      }
    }
    base += btot;
    __syncthreads();
  }
  if (tid == 0) cnt[e] = (base < CAP) ? base : CAP;
}

// ============ up-proj v2: 256x256 stacked-B GEMM, counted-vmcnt pipeline ===
// B panel = [B1(nt) 128 rows | B3(nt) 128 rows] (transposed weights, rows=out cols).
// K split into 32 chunks of K=32; 4 LDS chunk-slots x (A 16KB + B 16KB) = 128KB.
// Steady state: 3 chunks (12 loads) in flight, s_waitcnt vmcnt(8) per phase —
// never drains to 0 in the main loop (T4). 2 phases/kt, 32 MFMA/phase/wave.
// Epilogue: waves wc>=2 (B3 product) exchange acc via LDS to wc<2 for silu*mul.
#define UPPH(S, STAGE_EXPR, WAIT_STMT)                                           \
  {                                                                              \
    const u16* aB = aRd + (S) * 16384;                                           \
    const u16* bB = bRd + (S) * 16384;                                           \
    bf16x8 av[8], bv[4];                                                         \
    _Pragma("unroll") for (int m = 0; m < 8; ++m)                                \
        av[m] = *reinterpret_cast<const bf16x8*>(aB + m * 512);                  \
    _Pragma("unroll") for (int n = 0; n < 4; ++n)                                \
        bv[n] = *reinterpret_cast<const bf16x8*>(bB + n * 512);                  \
    STAGE_EXPR;                                                                  \
    WAIT_STMT;                                                                   \
    __builtin_amdgcn_s_barrier();                                                \
    __builtin_amdgcn_s_setprio(1);                                               \
    _Pragma("unroll") for (int m = 0; m < 8; ++m)                                \
      _Pragma("unroll") for (int n = 0; n < 4; ++n)                              \
        acc[m][n] = __builtin_amdgcn_mfma_f32_16x16x32_bf16(av[m], bv[n],        \
                                                            acc[m][n], 0, 0, 0);\
    __builtin_amdgcn_s_setprio(0);                                               \
    __builtin_amdgcn_s_barrier();                                                \
  }

#define VM8 asm volatile("s_waitcnt vmcnt(8)" ::: "memory")
#define VM4 asm volatile("s_waitcnt vmcnt(4)" ::: "memory")
#define VM0 asm volatile("s_waitcnt vmcnt(0)" ::: "memory")

__global__ __launch_bounds__(512) void up8_kernel(const u16* __restrict__ X,
                                                  const u16* __restrict__ w1t,
                                                  const u16* __restrict__ w3t,
                                                  const u16* __restrict__ sw1t,
                                                  const u16* __restrict__ sw3t,
                                                  u16* __restrict__ hs,
                                                  u16* __restrict__ he,
                                                  const int* __restrict__ btok,
                                                  const int* __restrict__ cnt) {
  extern __shared__ __align__(16) u16 lds_raw[];   // 4 slots x 32KB = 128KB
  const int tid = threadIdx.x, wid = tid >> 6, lane = tid & 63;
  const int bid = blockIdx.x;
  const int xcd = bid & 7, off = bid >> 3;   // off 0..191
  bool expert;
  int mt, nt, e = 0;
  const u16 *B1, *B3;
  u16* H;
  if (off < 160) {
    expert = true;
    int id = xcd * 160 + off;
    e = id / 40;
    int r = id % 40;
    mt = r % 5;
    nt = r / 5;
    if (mt * 256 >= cnt[e]) return;
    B1 = w1t + ((size_t)e << 20);
    B3 = w3t + ((size_t)e << 20);
    H = he + (size_t)(e * CAP + mt * 256) * 1024;
  } else {
    expert = false;
    int id = xcd * 32 + (off - 160);
    mt = id % 32;
    nt = id / 32;
    B1 = sw1t;
    B3 = sw3t;
    H = hs + (size_t)mt * 256 * 1024;
  }
  const int wr = wid >> 2, wc = wid & 3;        // 2 x 4 wave grid
  const int fr = lane & 15, fw = lane >> 4;

  // staging geometry: chunk = 256 rows x 32 elems (64B rows, 4 lanes/row)
  const int srow = tid >> 2;                    // 0..127
  const int slot = tid & 3;
  const int sw = ((slot ^ (srow & 3)) << 3);    // pre-swizzled source col (elems)

  const u16* aP[2];
#pragma unroll
  for (int j = 0; j < 2; ++j) {
    int row = mt * 256 + j * 128 + srow;
    int grow;
    if (expert) {
      int t0 = btok[e * CAP + row];
      grow = (t0 < 0) ? 0 : t0;
    } else {
      grow = row;
    }
    aP[j] = X + (size_t)grow * 1024 + sw;
  }
  const u16* bP[2];
  bP[0] = B1 + (size_t)(nt * 128 + srow) * 1024 + sw;   // B rows 0..127  = B1
  bP[1] = B3 + (size_t)(nt * 128 + srow) * 1024 + sw;   // B rows 128..255 = B3

  const int sdst = wid * 512;                   // wave-uniform LDS elem offset

  auto stage = [&](int c) {                     // chunk c = kt*2 + khalf
    u16* dA = lds_raw + (c & 3) * 16384 + sdst;
    u16* dB = dA + 8192;
    const int g = c * 32;                       // global col = kt*64 + h*32
    gload16(aP[0] + g, dA);
    gload16(aP[1] + g, dA + 4096);
    gload16(bP[0] + g, dB);
    gload16(bP[1] + g, dB + 4096);
  };

  // frag-read base pointers (swizzle slot is lane-constant: r&3 == fr&3)
  const int swz = ((fw ^ (fr & 3)) << 3);
  const u16* aRd = lds_raw + (wr * 128 + fr) * 32 + swz;
  const u16* bRd = lds_raw + 8192 + (wc * 64 + fr) * 32 + swz;

  f32x4 acc[8][4] = {};

  stage(0);
  stage(1);
  stage(2);
  VM8;                                          // chunk 0 landed (1,2 in flight)
  __builtin_amdgcn_s_barrier();

  // phases 0..27 (kt 0..13): always stage p+3, always vmcnt(8)
  for (int t = 0; t < 7; ++t) {
    const int p0 = t * 4;
    UPPH(0, stage(p0 + 3), VM8)
    UPPH(1, stage(p0 + 4), VM8)
    UPPH(2, stage(p0 + 5), VM8)
    UPPH(3, stage(p0 + 6), VM8)
  }
  // phases 28..31: stage last chunk, then drain 8 -> 4 -> 0
  UPPH(0, stage(31), VM8)
  UPPH(1, (void)0, VM4)
  UPPH(2, (void)0, VM0)
  UPPH(3, (void)0, (void)0)

  // ---- epilogue: cross-wave silu combine via LDS (conflict-free layout)
  float* lf = reinterpret_cast<float*>(lds_raw);
  if (wc >= 2) {
    float* dst = lf + (wr * 2 + (wc - 2)) * 8192 + lane;
#pragma unroll
    for (int m = 0; m < 8; ++m)
#pragma unroll
      for (int n = 0; n < 4; ++n)
#pragma unroll
        for (int ri = 0; ri < 4; ++ri)
          dst[(m * 16 + n * 4 + ri) * 64] = acc[m][n][ri];
  }
  __syncthreads();
  if (wc < 2) {
    const float* src = lf + (wr * 2 + wc) * 8192 + lane;
    const int row0 = wr * 128 + fw * 4;
    const int col0 = nt * 128 + wc * 64;
#pragma unroll
    for (int m = 0; m < 8; ++m)
#pragma unroll
      for (int n = 0; n < 4; ++n)
#pragma unroll
        for (int ri = 0; ri < 4; ++ri) {
          float v1 = acc[m][n][ri];
          float v3 = src[(m * 16 + n * 4 + ri) * 64];
          float h = (v1 / (1.f + __expf(-v1))) * v3;
          H[(size_t)(row0 + m * 16 + ri) * 1024 + col0 + n * 16 + fr] = f2bf(h);
        }
  }
}

// ---------------- down-proj, 256x256 tile, 8 waves, 4-phase K-tiles -------
// Grid 768 = 8 XCD chunks x (80 expert + 16 shared) for balance.
__global__ __launch_bounds__(512) void down8_kernel(const u16* __restrict__ hs,
                                                    const u16* __restrict__ he,
                                                    const u16* __restrict__ sB,
                                                    const u16* __restrict__ eB,
                                                    float* __restrict__ Out,
                                                    u16* __restrict__ OutB,
                                                    const float* __restrict__ bw,
                                                    const int* __restrict__ cnt) {
  extern __shared__ __align__(16) u16 lds_raw[];   // 2 buf x (A,B) x 32KB = 128KB
  const int tid = threadIdx.x, wid = tid >> 6, lane = tid & 63;
  const int bid = blockIdx.x;
  const int xcd = bid & 7, off = bid >> 3;   // off 0..95
  bool expert;
  int mt, nt, e = 0;
  const u16 *Asrc, *Bsrc;
  if (off < 80) {
    expert = true;
    int id = xcd * 80 + off;
    e = id / 20;
    int r = id % 20;
    mt = r % 5;
    nt = r / 5;
    if (mt * 256 >= cnt[e]) return;
    Asrc = he + (size_t)e * CAP * 1024;
    Bsrc = eB + ((size_t)e << 20);
  } else {
    expert = false;
    int id = xcd * 16 + (off - 80);
    mt = id % 32;
    nt = id / 32;
    Asrc = hs;
    Bsrc = sB;
  }
  const int wr = wid >> 2, wc = wid & 3;

  const int srow = wid * 8 + (lane >> 3);
  const int sslot = lane & 7;
  const int swin = ((sslot ^ (srow & 7)) << 3);
  const u16* aS = Asrc + (size_t)(mt * 256 + srow) * 1024 + swin;
  const u16* bS = Bsrc + (size_t)(nt * 256 + srow) * 1024 + swin;

  auto ldsA = [&](int b) { return lds_raw + b * 32768; };
  auto ldsB = [&](int b) { return lds_raw + b * 32768 + 16384; };

  auto stageA = [&](int b, int kt) {
    u16* base = ldsA(b);
#pragma unroll
    for (int j = 0; j < 4; ++j)
      gload16(aS + (size_t)j * 64 * 1024 + kt * 64, base + (j * 64 + wid * 8) * 64);
  };
  auto stageB = [&](int b, int kt) {
    u16* base = ldsB(b);
#pragma unroll
    for (int j = 0; j < 4; ++j)
      gload16(bS + (size_t)j * 64 * 1024 + kt * 64, base + (j * 64 + wid * 8) * 64);
  };

  const int fr = lane & 15, fw = lane >> 4;
  auto Afrag = [&](int cur, int m, int ks) -> bf16x8 {
    int r = wr * 128 + m * 16 + fr;
    int W = ks * 4 + fw;
    return *reinterpret_cast<const bf16x8*>(ldsA(cur) + r * 64 + ((W ^ (r & 7)) << 3));
  };
  auto Bfrag = [&](int cur, int n, int ks) -> bf16x8 {
    int r = wc * 64 + n * 16 + fr;
    int W = ks * 4 + fw;
    return *reinterpret_cast<const bf16x8*>(ldsB(cur) + r * 64 + ((W ^ (r & 7)) << 3));
  };

  f32x4 acc[8][4] = {};

  stageA(0, 0);
  stageB(0, 0);
  asm volatile("s_waitcnt vmcnt(0)" ::: "memory");
  __builtin_amdgcn_s_barrier();

  for (int kt = 0; kt < 16; ++kt) {
    const int cur = kt & 1;
    const bool pf = (kt + 1 < 16);
    bf16x8 bfr[4][2];
#pragma unroll
    for (int n = 0; n < 4; ++n) {
      bfr[n][0] = Bfrag(cur, n, 0);
      bfr[n][1] = Bfrag(cur, n, 1);
    }
    // ---- phase 0: m0,m1 ; prefetch A(kt+1)
    {
      bf16x8 a00 = Afrag(cur, 0, 0), a01 = Afrag(cur, 0, 1);
      bf16x8 a10 = Afrag(cur, 1, 0), a11 = Afrag(cur, 1, 1);
      if (pf) stageA(cur ^ 1, kt + 1);
      __builtin_amdgcn_s_barrier();
      __builtin_amdgcn_s_setprio(1);
#pragma unroll
      for (int n = 0; n < 4; ++n) {
        acc[0][n] = __builtin_amdgcn_mfma_f32_16x16x32_bf16(a00, bfr[n][0], acc[0][n], 0, 0, 0);
        acc[0][n] = __builtin_amdgcn_mfma_f32_16x16x32_bf16(a01, bfr[n][1], acc[0][n], 0, 0, 0);
        acc[1][n] = __builtin_amdgcn_mfma_f32_16x16x32_bf16(a10, bfr[n][0], acc[1][n], 0, 0, 0);
        acc[1][n] = __builtin_amdgcn_mfma_f32_16x16x32_bf16(a11, bfr[n][1], acc[1][n], 0, 0, 0);
      }
      __builtin_amdgcn_s_setprio(0);
      __builtin_amdgcn_s_barrier();
    }
    // ---- phase 1: m2,m3 ; prefetch B(kt+1)
    {
      bf16x8 a00 = Afrag(cur, 2, 0), a01 = Afrag(cur, 2, 1);
      bf16x8 a10 = Afrag(cur, 3, 0), a11 = Afrag(cur, 3, 1);
      if (pf) stageB(cur ^ 1, kt + 1);
      __builtin_amdgcn_s_barrier();
      __builtin_amdgcn_s_setprio(1);
#pragma unroll
      for (int n = 0; n < 4; ++n) {
        acc[2][n] = __builtin_amdgcn_mfma_f32_16x16x32_bf16(a00, bfr[n][0], acc[2][n], 0, 0, 0);
        acc[2][n] = __builtin_amdgcn_mfma_f32_16x16x32_bf16(a01, bfr[n][1], acc[2][n], 0, 0, 0);
        acc[3][n] = __builtin_amdgcn_mfma_f32_16x16x32_bf16(a10, bfr[n][0], acc[3][n], 0, 0, 0);
        acc[3][n] = __builtin_amdgcn_mfma_f32_16x16x32_bf16(a11, bfr[n][1], acc[3][n], 0, 0, 0);
      }
      __builtin_amdgcn_s_setprio(0);
      __builtin_amdgcn_s_barrier();
    }
    // ---- phase 2: m4,m5
    {
      bf16x8 a00 = Afrag(cur, 4, 0), a01 = Afrag(cur, 4, 1);
      bf16x8 a10 = Afrag(cur, 5, 0), a11 = Afrag(cur, 5, 1);
      __builtin_amdgcn_s_barrier();
      __builtin_amdgcn_s_setprio(1);
#pragma unroll
      for (int n = 0; n < 4; ++n) {
        acc[4][n] = __builtin_amdgcn_mfma_f32_16x16x32_bf16(a00, bfr[n][0], acc[4][n], 0, 0, 0);
        acc[4][n] = __builtin_amdgcn_mfma_f32_16x16x32_bf16(a01, bfr[n][1], acc[4][n], 0, 0, 0);
        acc[5][n] = __builtin_amdgcn_mfma_f32_16x16x32_bf16(a10, bfr[n][0], acc[5][n], 0, 0, 0);
        acc[5][n] = __builtin_amdgcn_mfma_f32_16x16x32_bf16(a11, bfr[n][1], acc[5][n], 0, 0, 0);
      }
      __builtin_amdgcn_s_setprio(0);
      __builtin_amdgcn_s_barrier();
    }
    // ---- phase 3: m6,m7 ; drain once per K-tile
    {
      bf16x8 a00 = Afrag(cur, 6, 0), a01 = Afrag(cur, 6, 1);
      bf16x8 a10 = Afrag(cur, 7, 0), a11 = Afrag(cur, 7, 1);
      __builtin_amdgcn_s_barrier();
      __builtin_amdgcn_s_setprio(1);
#pragma unroll
      for (int n = 0; n < 4; ++n) {
        acc[6][n] = __builtin_amdgcn_mfma_f32_16x16x32_bf16(a00, bfr[n][0], acc[6][n], 0, 0, 0);
        acc[6][n] = __builtin_amdgcn_mfma_f32_16x16x32_bf16(a01, bfr[n][1], acc[6][n], 0, 0, 0);
        acc[7][n] = __builtin_amdgcn_mfma_f32_16x16x32_bf16(a10, bfr[n][0], acc[7][n], 0, 0, 0);
        acc[7][n] = __builtin_amdgcn_mfma_f32_16x16x32_bf16(a11, bfr[n][1], acc[7][n], 0, 0, 0);
      }
      __builtin_amdgcn_s_setprio(0);
      asm volatile("s_waitcnt vmcnt(0)" ::: "memory");
      __builtin_amdgcn_s_barrier();
    }
  }

  // ---- epilogue
  const int orow0 = mt * 256 + wr * 128 + fw * 4;
  const int ocol0 = nt * 256 + wc * 64;
  if (expert) {
#pragma unroll
    for (int m = 0; m < 8; ++m)
#pragma unroll
      for (int ri = 0; ri < 4; ++ri) {
        int row = orow0 + m * 16 + ri;
        int slot = e * CAP + row;
        float wgt = bw[slot];
#pragma unroll
        for (int n = 0; n < 4; ++n)
          OutB[(size_t)slot * 1024 + ocol0 + n * 16 + fr] = f2bf(acc[m][n][ri] * wgt);
      }
  } else {
#pragma unroll
    for (int m = 0; m < 8; ++m)
#pragma unroll
      for (int ri = 0; ri < 4; ++ri) {
        int row = orow0 + m * 16 + ri;
#pragma unroll
        for (int n = 0; n < 4; ++n)
          Out[(size_t)row * 1024 + ocol0 + n * 16 + fr] = acc[m][n][ri];
      }
  }
}

// ---------------- combine: out[t] += sum_k oe[tslot[t,k]] ----------------
__global__ __launch_bounds__(256) void combine_kernel(const u16* __restrict__ oe,
                                                      const int* __restrict__ tslot,
                                                      float* __restrict__ out) {
  const int t = blockIdx.x;
  const int c = threadIdx.x;
  int s0 = tslot[t * 4 + 0], s1 = tslot[t * 4 + 1];
  int s2 = tslot[t * 4 + 2], s3 = tslot[t * 4 + 3];
  float4 v = reinterpret_cast<float4*>(out + (size_t)t * 1024)[c];
  auto addsl = [&](int s) {
    if (s >= 0) {
      uint2 q = reinterpret_cast<const uint2*>(oe + (size_t)s * 1024)[c];
      v.x += bf2f((u16)(q.x & 0xffff));
      v.y += bf2f((u16)(q.x >> 16));
      v.z += bf2f((u16)(q.y & 0xffff));
      v.w += bf2f((u16)(q.y >> 16));
    }
  };
  addsl(s0); addsl(s1); addsl(s2); addsl(s3);
  reinterpret_cast<float4*>(out + (size_t)t * 1024)[c] = v;
}

extern "C" void kernel_launch(void* const* d_in, const int* in_sizes, int n_in,
                              void* d_out, int out_size, void* d_ws, size_t ws_size,
                              hipStream_t stream) {
  const float* x   = (const float*)d_in[0];
  const float* wg  = (const float*)d_in[1];
  const float* w1  = (const float*)d_in[2];
  const float* w2  = (const float*)d_in[3];
  const float* w3  = (const float*)d_in[4];
  const float* sw1 = (const float*)d_in[5];
  const float* sw2 = (const float*)d_in[6];
  const float* sw3 = (const float*)d_in[7];
  float* out = (float*)d_out;

  char* p = (char*)d_ws;
  auto alloc = [&](size_t bytes) {
    char* q = p;
    p += (bytes + 255) & ~(size_t)255;
    return q;
  };
  u16* xb   = (u16*)alloc((size_t)NTOK * 1024 * 2);
  u16* w1t  = (u16*)alloc((size_t)NEXP * 1024 * 1024 * 2);
  u16* w3t  = (u16*)alloc((size_t)NEXP * 1024 * 1024 * 2);
  u16* w2t  = (u16*)alloc((size_t)NEXP * 1024 * 1024 * 2);
  u16* sw1t = (u16*)alloc((size_t)1024 * 1024 * 2);
  u16* sw3t = (u16*)alloc((size_t)1024 * 1024 * 2);
  u16* sw2t = (u16*)alloc((size_t)1024 * 1024 * 2);
  u16* hs   = (u16*)alloc((size_t)NTOK * 1024 * 2);
  u16* he   = (u16*)alloc((size_t)NEXP * CAP * 1024 * 2);
  int*   gidx = (int*)alloc((size_t)NTOK * 4 * 4);
  float* gww  = (float*)alloc((size_t)NTOK * 4 * 4);
  int*   btok = (int*)alloc((size_t)NEXP * CAP * 4);
  float* bww  = (float*)alloc((size_t)NEXP * CAP * 4);
  int*   cnt  = (int*)alloc((size_t)NEXP * 4);
  int*   tslot= (int*)alloc((size_t)NTOK * 4 * 4);
  // slot-output buffer overlays w1t/w3t (dead after up8_kernel):
  u16* oe = w1t;

  // 1. converts / transposes
  conv_x_kernel<<<NTOK * 1024 / 1024, 256, 0, stream>>>(x, xb);
  tconv_all_kernel<<<dim3(32, 32, 99), 256, 0, stream>>>(w1, w3, w2, sw1, sw3, sw2,
                                                         w1t, w3t, w2t, sw1t, sw3t, sw2t);
  // 2. gating + dispatch
  gate_kernel<<<NTOK, 256, 0, stream>>>(x, wg, gidx, gww);
  initbuf_kernel<<<(NEXP * CAP + 255) / 256, 256, 0, stream>>>(btok, bww);
  rank_kernel<<<NEXP, 1024, 0, stream>>>(gidx, gww, btok, bww, cnt, tslot);
  // 3. up (expert + shared, XCD-balanced, 128KB dynamic LDS, counted vmcnt)
  up8_kernel<<<1536, 512, 131072, stream>>>(xb, w1t, w3t, sw1t, sw3t, hs, he, btok, cnt);
  // 4. down (expert + shared, XCD-balanced, 128KB dynamic LDS)
  down8_kernel<<<768, 512, 131072, stream>>>(hs, he, sw2t, w2t, out, oe, bww, cnt);
  // 5. gather-combine expert contributions into out
  combine_kernel<<<NTOK, 256, 0, stream>>>(oe, tslot, out);
}

// Round 2
// 580.943 us; speedup vs baseline: 1.0211x; 1.0211x over previous
//
#include <hip/hip_runtime.h>
#include <stdint.h>

#define NTOK 8192
#define CAP  1280
#define NEXP 32

typedef __bf16 bf16x8 __attribute__((ext_vector_type(8)));
typedef float f32x4 __attribute__((ext_vector_type(4)));
typedef unsigned short u16;

__device__ __forceinline__ u16 f2bf(float f) {
  unsigned u = __builtin_bit_cast(unsigned, f);
  u = (u + 0x7fffu + ((u >> 16) & 1u)) >> 16;
  return (u16)u;
}
__device__ __forceinline__ float bf2f(u16 h) {
  return __builtin_bit_cast(float, ((unsigned)h) << 16);
}

__device__ __forceinline__ void gload16(const void* g, void* l) {
  __builtin_amdgcn_global_load_lds(
      (const __attribute__((address_space(1))) void*)g,
      (__attribute__((address_space(3))) void*)l, 16, 0, 0);
}

// ---------------- convert x (fp32 -> bf16), 4 elems/thread ----------------
__global__ __launch_bounds__(256) void conv_x_kernel(const float* __restrict__ in,
                                                     u16* __restrict__ out) {
  int i = blockIdx.x * 256 + threadIdx.x;
  float4 v = reinterpret_cast<const float4*>(in)[i];
  uint2 o;
  o.x = (unsigned)f2bf(v.x) | ((unsigned)f2bf(v.y) << 16);
  o.y = (unsigned)f2bf(v.z) | ((unsigned)f2bf(v.w) << 16);
  reinterpret_cast<uint2*>(out)[i] = o;
}

// -------- transpose+convert 1024x1024 fp32 -> bf16, all weights in one ----
__global__ __launch_bounds__(256) void tconv_all_kernel(
    const float* __restrict__ w1, const float* __restrict__ w3,
    const float* __restrict__ w2, const float* __restrict__ sw1,
    const float* __restrict__ sw3, const float* __restrict__ sw2,
    u16* __restrict__ w1t, u16* __restrict__ w3t, u16* __restrict__ w2t,
    u16* __restrict__ sw1t, u16* __restrict__ sw3t, u16* __restrict__ sw2t) {
  __shared__ float tile[32][33];
  const int z = blockIdx.z;
  const float* src;
  u16* dst;
  if (z < 32)      { src = w1 + (size_t)z * 1048576;        dst = w1t + (size_t)z * 1048576; }
  else if (z < 64) { src = w3 + (size_t)(z - 32) * 1048576; dst = w3t + (size_t)(z - 32) * 1048576; }
  else if (z < 96) { src = w2 + (size_t)(z - 64) * 1048576; dst = w2t + (size_t)(z - 64) * 1048576; }
  else if (z == 96){ src = sw1; dst = sw1t; }
  else if (z == 97){ src = sw3; dst = sw3t; }
  else             { src = sw2; dst = sw2t; }
  int r0 = blockIdx.x * 32, c0 = blockIdx.y * 32;
  int tid = threadIdx.x;
#pragma unroll
  for (int i = 0; i < 4; ++i) {
    int t = tid + i * 256, r = t >> 5, c = t & 31;
    tile[r][c] = src[(size_t)(r0 + r) * 1024 + (c0 + c)];
  }
  __syncthreads();
#pragma unroll
  for (int i = 0; i < 4; ++i) {
    int t = tid + i * 256, cc = t >> 5, rr = t & 31;
    dst[(size_t)(c0 + cc) * 1024 + (r0 + rr)] = f2bf(tile[rr][cc]);
  }
}

// ---------------- gating: one block per token ----------------
__global__ __launch_bounds__(256) void gate_kernel(const float* __restrict__ x,
                                                   const float* __restrict__ wg,
                                                   int* __restrict__ gidx,
                                                   float* __restrict__ gw) {
  const int t = blockIdx.x;
  __shared__ float xl[1024];
  __shared__ float logits[32];
  const int tid = threadIdx.x;
  reinterpret_cast<float4*>(xl)[tid] = reinterpret_cast<const float4*>(x + (size_t)t * 1024)[tid];
  __syncthreads();
  const int e = tid >> 3, p = tid & 7;
  const float4* wrow = reinterpret_cast<const float4*>(wg + (size_t)e * 1024);
  const float4* xv4 = reinterpret_cast<const float4*>(xl);
  float s = 0.f;
#pragma unroll
  for (int i = 0; i < 32; ++i) {
    int c = p + 8 * i;
    float4 xv = xv4[c];
    float4 wv = wrow[c];
    s += xv.x * wv.x + xv.y * wv.y + xv.z * wv.z + xv.w * wv.w;
  }
  s += __shfl_xor(s, 1);
  s += __shfl_xor(s, 2);
  s += __shfl_xor(s, 4);
  if (p == 0) logits[e] = s;
  __syncthreads();
  if (tid == 0) {
    float m = logits[0];
#pragma unroll
    for (int i = 1; i < 32; ++i) m = fmaxf(m, logits[i]);
    float sum = 0.f;
#pragma unroll
    for (int i = 0; i < 32; ++i) sum += expf(logits[i] - m);
    float gm[8];
#pragma unroll
    for (int g = 0; g < 8; ++g) {
      float v = logits[4 * g];
      v = fmaxf(v, logits[4 * g + 1]);
      v = fmaxf(v, logits[4 * g + 2]);
      v = fmaxf(v, logits[4 * g + 3]);
      gm[g] = v;
    }
    unsigned gkeep = 0;
    for (int it = 0; it < 4; ++it) {
      float best = -3.4e38f; int bg = 0;
#pragma unroll
      for (int g = 0; g < 8; ++g) {
        bool ok = !((gkeep >> g) & 1u);
        if (ok && gm[g] > best) { best = gm[g]; bg = g; }
      }
      gkeep |= 1u << bg;
    }
    unsigned allow = 0;
#pragma unroll
    for (int g = 0; g < 8; ++g)
      if ((gkeep >> g) & 1u) allow |= 0xFu << (4 * g);
    unsigned taken = 0;
    float wsum = 0.f;
    int ids[4]; float wv[4];
    for (int sIt = 0; sIt < 4; ++sIt) {
      float best = -3.4e38f; int be = 0;
#pragma unroll
      for (int i = 0; i < 32; ++i) {
        bool ok = ((allow >> i) & 1u) && !((taken >> i) & 1u);
        float v = logits[i];
        if (ok && v > best) { best = v; be = i; }
      }
      taken |= 1u << be;
      ids[sIt] = be;
      float wq = expf(logits[be] - m) / sum;
      wv[sIt] = wq;
      wsum += wq;
    }
    float inv = 1.f / (wsum + 1e-9f);
#pragma unroll
    for (int sIt = 0; sIt < 4; ++sIt) {
      gidx[t * 4 + sIt] = ids[sIt];
      gw[t * 4 + sIt] = wv[sIt] * inv;
    }
  }
}

// ---------------- init dispatch buffers ----------------
__global__ __launch_bounds__(256) void initbuf_kernel(int* __restrict__ bt, float* __restrict__ bw) {
  int i = blockIdx.x * 256 + threadIdx.x;
  if (i < NEXP * CAP) { bt[i] = -1; bw[i] = 0.f; }
}

// ---------------- rank/dispatch: one block per expert, 1024 threads --------
__global__ __launch_bounds__(1024) void rank_kernel(const int* __restrict__ gidx,
                                                    const float* __restrict__ gw,
                                                    int* __restrict__ buf_tok,
                                                    float* __restrict__ buf_w,
                                                    int* __restrict__ cnt,
                                                    int* __restrict__ tslot) {
  const int e = blockIdx.x;
  const int tid = threadIdx.x, wid = tid >> 6, lane = tid & 63;
  __shared__ int wtot[16];
  int base = 0;
  for (int j0 = 0; j0 < NTOK * 4; j0 += 1024) {
    int j = j0 + tid;
    bool match = (gidx[j] == e);
    unsigned long long mb = __ballot(match);
    if (lane == 0) wtot[wid] = __popcll(mb);
    __syncthreads();
    int woff = 0, btot = 0;
#pragma unroll
    for (int w = 0; w < 16; ++w) {
      int c = wtot[w];
      if (w < wid) woff += c;
      btot += c;
    }
    if (match) {
      int pos = base + woff + __popcll(mb & ((1ull << lane) - 1ull));
      if (pos < CAP) {
        buf_tok[e * CAP + pos] = j >> 2;
        buf_w[e * CAP + pos] = gw[j];
        tslot[j] = e * CAP + pos;
      } else {
        tslot[j] = -1;
      }
    }
    base += btot;
    __syncthreads();
  }
  if (tid == 0) cnt[e] = (base < CAP) ? base : CAP;
}

// ============ up-proj v3: 256x256 stacked-B GEMM, counted-vmcnt pipeline ===
// B panel = [B1(nt) 128 rows | B3(nt) 128 rows] (transposed weights, rows=out cols).
// K split into 32 chunks of K=32; 4 LDS chunk-slots x (A 16KB + B 16KB) = 128KB.
// Steady state: 3 chunks (12 loads) in flight, s_waitcnt vmcnt(8) per phase —
// never drains to 0 in the main loop (T4). 2 phases/kt, 32 MFMA/phase/wave.
// Bank swizzle: rows are 64B (span 16 banks, parity picks half); slot XOR must
// use row bits ABOVE parity: s = fw ^ ((r>>1)&3)  ->  2-way (free). v2's
// s = fw ^ (r&3) collapsed with parity -> 4-way conflict (1.73e7 measured).
// Epilogue: waves wc>=2 (B3 product) exchange acc via LDS to wc<2 for silu*mul.
#define UPPH(S, STAGE_EXPR, WAIT_STMT)                                           \
  {                                                                              \
    const u16* aB = aRd + (S) * 16384;                                           \
    const u16* bB = bRd + (S) * 16384;                                           \
    bf16x8 av[8], bv[4];                                                         \
    _Pragma("unroll") for (int m = 0; m < 8; ++m)                                \
        av[m] = *reinterpret_cast<const bf16x8*>(aB + m * 512);                  \
    _Pragma("unroll") for (int n = 0; n < 4; ++n)                                \
        bv[n] = *reinterpret_cast<const bf16x8*>(bB + n * 512);                  \
    STAGE_EXPR;                                                                  \
    WAIT_STMT;                                                                   \
    __builtin_amdgcn_s_barrier();                                                \
    __builtin_amdgcn_s_setprio(1);                                               \
    _Pragma("unroll") for (int m = 0; m < 8; ++m)                                \
      _Pragma("unroll") for (int n = 0; n < 4; ++n)                              \
        acc[m][n] = __builtin_amdgcn_mfma_f32_16x16x32_bf16(av[m], bv[n],        \
                                                            acc[m][n], 0, 0, 0);\
    __builtin_amdgcn_s_setprio(0);                                               \
    __builtin_amdgcn_s_barrier();                                                \
  }

#define VM8 asm volatile("s_waitcnt vmcnt(8)" ::: "memory")
#define VM4 asm volatile("s_waitcnt vmcnt(4)" ::: "memory")
#define VM0 asm volatile("s_waitcnt vmcnt(0)" ::: "memory")

__global__ __launch_bounds__(512) void up8_kernel(const u16* __restrict__ X,
                                                  const u16* __restrict__ w1t,
                                                  const u16* __restrict__ w3t,
                                                  const u16* __restrict__ sw1t,
                                                  const u16* __restrict__ sw3t,
                                                  u16* __restrict__ hs,
                                                  u16* __restrict__ he,
                                                  const int* __restrict__ btok,
                                                  const int* __restrict__ cnt) {
  extern __shared__ __align__(16) u16 lds_raw[];   // 4 slots x 32KB = 128KB
  const int tid = threadIdx.x, wid = tid >> 6, lane = tid & 63;
  const int bid = blockIdx.x;
  const int xcd = bid & 7, off = bid >> 3;   // off 0..191
  bool expert;
  int mt, nt, e = 0;
  const u16 *B1, *B3;
  u16* H;
  if (off < 160) {
    expert = true;
    int id = xcd * 160 + off;
    e = id / 40;
    int r = id % 40;
    mt = r % 5;
    nt = r / 5;
    if (mt * 256 >= cnt[e]) return;
    B1 = w1t + ((size_t)e << 20);
    B3 = w3t + ((size_t)e << 20);
    H = he + (size_t)(e * CAP + mt * 256) * 1024;
  } else {
    expert = false;
    int id = xcd * 32 + (off - 160);
    mt = id % 32;
    nt = id / 32;
    B1 = sw1t;
    B3 = sw3t;
    H = hs + (size_t)mt * 256 * 1024;
  }
  const int wr = wid >> 2, wc = wid & 3;        // 2 x 4 wave grid
  const int fr = lane & 15, fw = lane >> 4;

  // staging geometry: chunk = 256 rows x 32 elems (64B rows, 4 lanes/row)
  const int srow = tid >> 2;                    // 0..127
  const int slot = tid & 3;
  const int sw = ((slot ^ ((srow >> 1) & 3)) << 3);  // pre-swizzled src col (elems)

  const u16* aP[2];
#pragma unroll
  for (int j = 0; j < 2; ++j) {
    int row = mt * 256 + j * 128 + srow;
    int grow;
    if (expert) {
      int t0 = btok[e * CAP + row];
      grow = (t0 < 0) ? 0 : t0;
    } else {
      grow = row;
    }
    aP[j] = X + (size_t)grow * 1024 + sw;
  }
  const u16* bP[2];
  bP[0] = B1 + (size_t)(nt * 128 + srow) * 1024 + sw;   // B rows 0..127  = B1
  bP[1] = B3 + (size_t)(nt * 128 + srow) * 1024 + sw;   // B rows 128..255 = B3

  const int sdst = wid * 512;                   // wave-uniform LDS elem offset

  auto stage = [&](int c) {                     // chunk c = kt*2 + khalf
    u16* dA = lds_raw + (c & 3) * 16384 + sdst;
    u16* dB = dA + 8192;
    const int g = c * 32;                       // global col = kt*64 + h*32
    gload16(aP[0] + g, dA);
    gload16(aP[1] + g, dA + 4096);
    gload16(bP[0] + g, dB);
    gload16(bP[1] + g, dB + 4096);
  };

  // frag-read swizzle slot is lane-constant: ((row>>1)&3) == ((fr>>1)&3)
  // (row = 16*const + fr, const even)
  const int swz = ((fw ^ ((fr >> 1) & 3)) << 3);
  const u16* aRd = lds_raw + (wr * 128 + fr) * 32 + swz;
  const u16* bRd = lds_raw + 8192 + (wc * 64 + fr) * 32 + swz;

  f32x4 acc[8][4] = {};

  stage(0);
  stage(1);
  stage(2);
  VM8;                                          // chunk 0 landed (1,2 in flight)
  __builtin_amdgcn_s_barrier();

  // phases 0..27 (kt 0..13): always stage p+3, always vmcnt(8)
  for (int t = 0; t < 7; ++t) {
    const int p0 = t * 4;
    UPPH(0, stage(p0 + 3), VM8)
    UPPH(1, stage(p0 + 4), VM8)
    UPPH(2, stage(p0 + 5), VM8)
    UPPH(3, stage(p0 + 6), VM8)
  }
  // phases 28..31: stage last chunk, then drain 8 -> 4 -> 0
  UPPH(0, stage(31), VM8)
  UPPH(1, (void)0, VM4)
  UPPH(2, (void)0, VM0)
  UPPH(3, (void)0, (void)0)

  // ---- epilogue: cross-wave silu combine via LDS (conflict-free layout)
  float* lf = reinterpret_cast<float*>(lds_raw);
  if (wc >= 2) {
    float* dst = lf + (wr * 2 + (wc - 2)) * 8192 + lane;
#pragma unroll
    for (int m = 0; m < 8; ++m)
#pragma unroll
      for (int n = 0; n < 4; ++n)
#pragma unroll
        for (int ri = 0; ri < 4; ++ri)
          dst[(m * 16 + n * 4 + ri) * 64] = acc[m][n][ri];
  }
  __syncthreads();
  if (wc < 2) {
    const float* src = lf + (wr * 2 + wc) * 8192 + lane;
    const int row0 = wr * 128 + fw * 4;
    const int col0 = nt * 128 + wc * 64;
#pragma unroll
    for (int m = 0; m < 8; ++m)
#pragma unroll
      for (int n = 0; n < 4; ++n)
#pragma unroll
        for (int ri = 0; ri < 4; ++ri) {
          float v1 = acc[m][n][ri];
          float v3 = src[(m * 16 + n * 4 + ri) * 64];
          float h = (v1 / (1.f + __expf(-v1))) * v3;
          H[(size_t)(row0 + m * 16 + ri) * 1024 + col0 + n * 16 + fr] = f2bf(h);
        }
  }
}

// ---------------- down-proj, 256x256 tile, 8 waves, 4-phase K-tiles -------
// Grid 768 = 8 XCD chunks x (80 expert + 16 shared) for balance.
__global__ __launch_bounds__(512) void down8_kernel(const u16* __restrict__ hs,
                                                    const u16* __restrict__ he,
                                                    const u16* __restrict__ sB,
                                                    const u16* __restrict__ eB,
                                                    float* __restrict__ Out,
                                                    u16* __restrict__ OutB,
                                                    const float* __restrict__ bw,
                                                    const int* __restrict__ cnt) {
  extern __shared__ __align__(16) u16 lds_raw[];   // 2 buf x (A,B) x 32KB = 128KB
  const int tid = threadIdx.x, wid = tid >> 6, lane = tid & 63;
  const int bid = blockIdx.x;
  const int xcd = bid & 7, off = bid >> 3;   // off 0..95
  bool expert;
  int mt, nt, e = 0;
  const u16 *Asrc, *Bsrc;
  if (off < 80) {
    expert = true;
    int id = xcd * 80 + off;
    e = id / 20;
    int r = id % 20;
    mt = r % 5;
    nt = r / 5;
    if (mt * 256 >= cnt[e]) return;
    Asrc = he + (size_t)e * CAP * 1024;
    Bsrc = eB + ((size_t)e << 20);
  } else {
    expert = false;
    int id = xcd * 16 + (off - 80);
    mt = id % 32;
    nt = id / 32;
    Asrc = hs;
    Bsrc = sB;
  }
  const int wr = wid >> 2, wc = wid & 3;

  const int srow = wid * 8 + (lane >> 3);
  const int sslot = lane & 7;
  const int swin = ((sslot ^ (srow & 7)) << 3);
  const u16* aS = Asrc + (size_t)(mt * 256 + srow) * 1024 + swin;
  const u16* bS = Bsrc + (size_t)(nt * 256 + srow) * 1024 + swin;

  auto ldsA = [&](int b) { return lds_raw + b * 32768; };
  auto ldsB = [&](int b) { return lds_raw + b * 32768 + 16384; };

  auto stageA = [&](int b, int kt) {
    u16* base = ldsA(b);
#pragma unroll
    for (int j = 0; j < 4; ++j)
      gload16(aS + (size_t)j * 64 * 1024 + kt * 64, base + (j * 64 + wid * 8) * 64);
  };
  auto stageB = [&](int b, int kt) {
    u16* base = ldsB(b);
#pragma unroll
    for (int j = 0; j < 4; ++j)
      gload16(bS + (size_t)j * 64 * 1024 + kt * 64, base + (j * 64 + wid * 8) * 64);
  };

  const int fr = lane & 15, fw = lane >> 4;
  auto Afrag = [&](int cur, int m, int ks) -> bf16x8 {
    int r = wr * 128 + m * 16 + fr;
    int W = ks * 4 + fw;
    return *reinterpret_cast<const bf16x8*>(ldsA(cur) + r * 64 + ((W ^ (r & 7)) << 3));
  };
  auto Bfrag = [&](int cur, int n, int ks) -> bf16x8 {
    int r = wc * 64 + n * 16 + fr;
    int W = ks * 4 + fw;
    return *reinterpret_cast<const bf16x8*>(ldsB(cur) + r * 64 + ((W ^ (r & 7)) << 3));
  };

  f32x4 acc[8][4] = {};

  stageA(0, 0);
  stageB(0, 0);
  asm volatile("s_waitcnt vmcnt(0)" ::: "memory");
  __builtin_amdgcn_s_barrier();

  for (int kt = 0; kt < 16; ++kt) {
    const int cur = kt & 1;
    const bool pf = (kt + 1 < 16);
    bf16x8 bfr[4][2];
#pragma unroll
    for (int n = 0; n < 4; ++n) {
      bfr[n][0] = Bfrag(cur, n, 0);
      bfr[n][1] = Bfrag(cur, n, 1);
    }
    // ---- phase 0: m0,m1 ; prefetch A(kt+1)
    {
      bf16x8 a00 = Afrag(cur, 0, 0), a01 = Afrag(cur, 0, 1);
      bf16x8 a10 = Afrag(cur, 1, 0), a11 = Afrag(cur, 1, 1);
      if (pf) stageA(cur ^ 1, kt + 1);
      __builtin_amdgcn_s_barrier();
      __builtin_amdgcn_s_setprio(1);
#pragma unroll
      for (int n = 0; n < 4; ++n) {
        acc[0][n] = __builtin_amdgcn_mfma_f32_16x16x32_bf16(a00, bfr[n][0], acc[0][n], 0, 0, 0);
        acc[0][n] = __builtin_amdgcn_mfma_f32_16x16x32_bf16(a01, bfr[n][1], acc[0][n], 0, 0, 0);
        acc[1][n] = __builtin_amdgcn_mfma_f32_16x16x32_bf16(a10, bfr[n][0], acc[1][n], 0, 0, 0);
        acc[1][n] = __builtin_amdgcn_mfma_f32_16x16x32_bf16(a11, bfr[n][1], acc[1][n], 0, 0, 0);
      }
      __builtin_amdgcn_s_setprio(0);
      __builtin_amdgcn_s_barrier();
    }
    // ---- phase 1: m2,m3 ; prefetch B(kt+1)
    {
      bf16x8 a00 = Afrag(cur, 2, 0), a01 = Afrag(cur, 2, 1);
      bf16x8 a10 = Afrag(cur, 3, 0), a11 = Afrag(cur, 3, 1);
      if (pf) stageB(cur ^ 1, kt + 1);
      __builtin_amdgcn_s_barrier();
      __builtin_amdgcn_s_setprio(1);
#pragma unroll
      for (int n = 0; n < 4; ++n) {
        acc[2][n] = __builtin_amdgcn_mfma_f32_16x16x32_bf16(a00, bfr[n][0], acc[2][n], 0, 0, 0);
        acc[2][n] = __builtin_amdgcn_mfma_f32_16x16x32_bf16(a01, bfr[n][1], acc[2][n], 0, 0, 0);
        acc[3][n] = __builtin_amdgcn_mfma_f32_16x16x32_bf16(a10, bfr[n][0], acc[3][n], 0, 0, 0);
        acc[3][n] = __builtin_amdgcn_mfma_f32_16x16x32_bf16(a11, bfr[n][1], acc[3][n], 0, 0, 0);
      }
      __builtin_amdgcn_s_setprio(0);
      __builtin_amdgcn_s_barrier();
    }
    // ---- phase 2: m4,m5
    {
      bf16x8 a00 = Afrag(cur, 4, 0), a01 = Afrag(cur, 4, 1);
      bf16x8 a10 = Afrag(cur, 5, 0), a11 = Afrag(cur, 5, 1);
      __builtin_amdgcn_s_barrier();
      __builtin_amdgcn_s_setprio(1);
#pragma unroll
      for (int n = 0; n < 4; ++n) {
        acc[4][n] = __builtin_amdgcn_mfma_f32_16x16x32_bf16(a00, bfr[n][0], acc[4][n], 0, 0, 0);
        acc[4][n] = __builtin_amdgcn_mfma_f32_16x16x32_bf16(a01, bfr[n][1], acc[4][n], 0, 0, 0);
        acc[5][n] = __builtin_amdgcn_mfma_f32_16x16x32_bf16(a10, bfr[n][0], acc[5][n], 0, 0, 0);
        acc[5][n] = __builtin_amdgcn_mfma_f32_16x16x32_bf16(a11, bfr[n][1], acc[5][n], 0, 0, 0);
      }
      __builtin_amdgcn_s_setprio(0);
      __builtin_amdgcn_s_barrier();
    }
    // ---- phase 3: m6,m7 ; drain once per K-tile
    {
      bf16x8 a00 = Afrag(cur, 6, 0), a01 = Afrag(cur, 6, 1);
      bf16x8 a10 = Afrag(cur, 7, 0), a11 = Afrag(cur, 7, 1);
      __builtin_amdgcn_s_barrier();
      __builtin_amdgcn_s_setprio(1);
#pragma unroll
      for (int n = 0; n < 4; ++n) {
        acc[6][n] = __builtin_amdgcn_mfma_f32_16x16x32_bf16(a00, bfr[n][0], acc[6][n], 0, 0, 0);
        acc[6][n] = __builtin_amdgcn_mfma_f32_16x16x32_bf16(a01, bfr[n][1], acc[6][n], 0, 0, 0);
        acc[7][n] = __builtin_amdgcn_mfma_f32_16x16x32_bf16(a10, bfr[n][0], acc[7][n], 0, 0, 0);
        acc[7][n] = __builtin_amdgcn_mfma_f32_16x16x32_bf16(a11, bfr[n][1], acc[7][n], 0, 0, 0);
      }
      __builtin_amdgcn_s_setprio(0);
      asm volatile("s_waitcnt vmcnt(0)" ::: "memory");
      __builtin_amdgcn_s_barrier();
    }
  }

  // ---- epilogue
  const int orow0 = mt * 256 + wr * 128 + fw * 4;
  const int ocol0 = nt * 256 + wc * 64;
  if (expert) {
#pragma unroll
    for (int m = 0; m < 8; ++m)
#pragma unroll
      for (int ri = 0; ri < 4; ++ri) {
        int row = orow0 + m * 16 + ri;
        int slot = e * CAP + row;
        float wgt = bw[slot];
#pragma unroll
        for (int n = 0; n < 4; ++n)
          OutB[(size_t)slot * 1024 + ocol0 + n * 16 + fr] = f2bf(acc[m][n][ri] * wgt);
      }
  } else {
#pragma unroll
    for (int m = 0; m < 8; ++m)
#pragma unroll
      for (int ri = 0; ri < 4; ++ri) {
        int row = orow0 + m * 16 + ri;
#pragma unroll
        for (int n = 0; n < 4; ++n)
          Out[(size_t)row * 1024 + ocol0 + n * 16 + fr] = acc[m][n][ri];
      }
  }
}

// ---------------- combine: out[t] += sum_k oe[tslot[t,k]] ----------------
__global__ __launch_bounds__(256) void combine_kernel(const u16* __restrict__ oe,
                                                      const int* __restrict__ tslot,
                                                      float* __restrict__ out) {
  const int t = blockIdx.x;
  const int c = threadIdx.x;
  int s0 = tslot[t * 4 + 0], s1 = tslot[t * 4 + 1];
  int s2 = tslot[t * 4 + 2], s3 = tslot[t * 4 + 3];
  float4 v = reinterpret_cast<float4*>(out + (size_t)t * 1024)[c];
  auto addsl = [&](int s) {
    if (s >= 0) {
      uint2 q = reinterpret_cast<const uint2*>(oe + (size_t)s * 1024)[c];
      v.x += bf2f((u16)(q.x & 0xffff));
      v.y += bf2f((u16)(q.x >> 16));
      v.z += bf2f((u16)(q.y & 0xffff));
      v.w += bf2f((u16)(q.y >> 16));
    }
  };
  addsl(s0); addsl(s1); addsl(s2); addsl(s3);
  reinterpret_cast<float4*>(out + (size_t)t * 1024)[c] = v;
}

extern "C" void kernel_launch(void* const* d_in, const int* in_sizes, int n_in,
                              void* d_out, int out_size, void* d_ws, size_t ws_size,
                              hipStream_t stream) {
  const float* x   = (const float*)d_in[0];
  const float* wg  = (const float*)d_in[1];
  const float* w1  = (const float*)d_in[2];
  const float* w2  = (const float*)d_in[3];
  const float* w3  = (const float*)d_in[4];
  const float* sw1 = (const float*)d_in[5];
  const float* sw2 = (const float*)d_in[6];
  const float* sw3 = (const float*)d_in[7];
  float* out = (float*)d_out;

  char* p = (char*)d_ws;
  auto alloc = [&](size_t bytes) {
    char* q = p;
    p += (bytes + 255) & ~(size_t)255;
    return q;
  };
  u16* xb   = (u16*)alloc((size_t)NTOK * 1024 * 2);
  u16* w1t  = (u16*)alloc((size_t)NEXP * 1024 * 1024 * 2);
  u16* w3t  = (u16*)alloc((size_t)NEXP * 1024 * 1024 * 2);
  u16* w2t  = (u16*)alloc((size_t)NEXP * 1024 * 1024 * 2);
  u16* sw1t = (u16*)alloc((size_t)1024 * 1024 * 2);
  u16* sw3t = (u16*)alloc((size_t)1024 * 1024 * 2);
  u16* sw2t = (u16*)alloc((size_t)1024 * 1024 * 2);
  u16* hs   = (u16*)alloc((size_t)NTOK * 1024 * 2);
  u16* he   = (u16*)alloc((size_t)NEXP * CAP * 1024 * 2);
  int*   gidx = (int*)alloc((size_t)NTOK * 4 * 4);
  float* gww  = (float*)alloc((size_t)NTOK * 4 * 4);
  int*   btok = (int*)alloc((size_t)NEXP * CAP * 4);
  float* bww  = (float*)alloc((size_t)NEXP * CAP * 4);
  int*   cnt  = (int*)alloc((size_t)NEXP * 4);
  int*   tslot= (int*)alloc((size_t)NTOK * 4 * 4);
  // slot-output buffer overlays w1t/w3t (dead after up8_kernel):
  u16* oe = w1t;

  // 1. converts / transposes
  conv_x_kernel<<<NTOK * 1024 / 1024, 256, 0, stream>>>(x, xb);
  tconv_all_kernel<<<dim3(32, 32, 99), 256, 0, stream>>>(w1, w3, w2, sw1, sw3, sw2,
                                                         w1t, w3t, w2t, sw1t, sw3t, sw2t);
  // 2. gating + dispatch
  gate_kernel<<<NTOK, 256, 0, stream>>>(x, wg, gidx, gww);
  initbuf_kernel<<<(NEXP * CAP + 255) / 256, 256, 0, stream>>>(btok, bww);
  rank_kernel<<<NEXP, 1024, 0, stream>>>(gidx, gww, btok, bww, cnt, tslot);
  // 3. up (expert + shared, XCD-balanced, 128KB dynamic LDS, counted vmcnt)
  up8_kernel<<<1536, 512, 131072, stream>>>(xb, w1t, w3t, sw1t, sw3t, hs, he, btok, cnt);
  // 4. down (expert + shared, XCD-balanced, 128KB dynamic LDS)
  down8_kernel<<<768, 512, 131072, stream>>>(hs, he, sw2t, w2t, out, oe, bww, cnt);
  // 5. gather-combine expert contributions into out
  combine_kernel<<<NTOK, 256, 0, stream>>>(oe, tslot, out);
}

// Round 3
// 578.224 us; speedup vs baseline: 1.0259x; 1.0047x over previous
//
#include <hip/hip_runtime.h>
#include <stdint.h>

#define NTOK 8192
#define CAP  1280
#define NEXP 32

typedef __bf16 bf16x8 __attribute__((ext_vector_type(8)));
typedef float f32x4 __attribute__((ext_vector_type(4)));
typedef unsigned short u16;

__device__ __forceinline__ u16 f2bf(float f) {
  unsigned u = __builtin_bit_cast(unsigned, f);
  u = (u + 0x7fffu + ((u >> 16) & 1u)) >> 16;
  return (u16)u;
}
__device__ __forceinline__ float bf2f(u16 h) {
  return __builtin_bit_cast(float, ((unsigned)h) << 16);
}

__device__ __forceinline__ void gload16(const void* g, void* l) {
  __builtin_amdgcn_global_load_lds(
      (const __attribute__((address_space(1))) void*)g,
      (__attribute__((address_space(3))) void*)l, 16, 0, 0);
}

#define VM0 asm volatile("s_waitcnt vmcnt(0)" ::: "memory")

// ---------------- convert x (fp32 -> bf16), 4 elems/thread ----------------
__global__ __launch_bounds__(256) void conv_x_kernel(const float* __restrict__ in,
                                                     u16* __restrict__ out) {
  int i = blockIdx.x * 256 + threadIdx.x;
  float4 v = reinterpret_cast<const float4*>(in)[i];
  uint2 o;
  o.x = (unsigned)f2bf(v.x) | ((unsigned)f2bf(v.y) << 16);
  o.y = (unsigned)f2bf(v.z) | ((unsigned)f2bf(v.w) << 16);
  reinterpret_cast<uint2*>(out)[i] = o;
}

// -------- transpose+convert 1024x1024 fp32 -> bf16, all weights in one ----
__global__ __launch_bounds__(256) void tconv_all_kernel(
    const float* __restrict__ w1, const float* __restrict__ w3,
    const float* __restrict__ w2, const float* __restrict__ sw1,
    const float* __restrict__ sw3, const float* __restrict__ sw2,
    u16* __restrict__ w1t, u16* __restrict__ w3t, u16* __restrict__ w2t,
    u16* __restrict__ sw1t, u16* __restrict__ sw3t, u16* __restrict__ sw2t) {
  __shared__ float tile[32][33];
  const int z = blockIdx.z;
  const float* src;
  u16* dst;
  if (z < 32)      { src = w1 + (size_t)z * 1048576;        dst = w1t + (size_t)z * 1048576; }
  else if (z < 64) { src = w3 + (size_t)(z - 32) * 1048576; dst = w3t + (size_t)(z - 32) * 1048576; }
  else if (z < 96) { src = w2 + (size_t)(z - 64) * 1048576; dst = w2t + (size_t)(z - 64) * 1048576; }
  else if (z == 96){ src = sw1; dst = sw1t; }
  else if (z == 97){ src = sw3; dst = sw3t; }
  else             { src = sw2; dst = sw2t; }
  int r0 = blockIdx.x * 32, c0 = blockIdx.y * 32;
  int tid = threadIdx.x;
#pragma unroll
  for (int i = 0; i < 4; ++i) {
    int t = tid + i * 256, r = t >> 5, c = t & 31;
    tile[r][c] = src[(size_t)(r0 + r) * 1024 + (c0 + c)];
  }
  __syncthreads();
#pragma unroll
  for (int i = 0; i < 4; ++i) {
    int t = tid + i * 256, cc = t >> 5, rr = t & 31;
    dst[(size_t)(c0 + cc) * 1024 + (r0 + rr)] = f2bf(tile[rr][cc]);
  }
}

// ---------------- gating: one block per token ----------------
__global__ __launch_bounds__(256) void gate_kernel(const float* __restrict__ x,
                                                   const float* __restrict__ wg,
                                                   int* __restrict__ gidx,
                                                   float* __restrict__ gw) {
  const int t = blockIdx.x;
  __shared__ float xl[1024];
  __shared__ float logits[32];
  const int tid = threadIdx.x;
  reinterpret_cast<float4*>(xl)[tid] = reinterpret_cast<const float4*>(x + (size_t)t * 1024)[tid];
  __syncthreads();
  const int e = tid >> 3, p = tid & 7;
  const float4* wrow = reinterpret_cast<const float4*>(wg + (size_t)e * 1024);
  const float4* xv4 = reinterpret_cast<const float4*>(xl);
  float s = 0.f;
#pragma unroll
  for (int i = 0; i < 32; ++i) {
    int c = p + 8 * i;
    float4 xv = xv4[c];
    float4 wv = wrow[c];
    s += xv.x * wv.x + xv.y * wv.y + xv.z * wv.z + xv.w * wv.w;
  }
  s += __shfl_xor(s, 1);
  s += __shfl_xor(s, 2);
  s += __shfl_xor(s, 4);
  if (p == 0) logits[e] = s;
  __syncthreads();
  if (tid == 0) {
    float m = logits[0];
#pragma unroll
    for (int i = 1; i < 32; ++i) m = fmaxf(m, logits[i]);
    float sum = 0.f;
#pragma unroll
    for (int i = 0; i < 32; ++i) sum += expf(logits[i] - m);
    float gm[8];
#pragma unroll
    for (int g = 0; g < 8; ++g) {
      float v = logits[4 * g];
      v = fmaxf(v, logits[4 * g + 1]);
      v = fmaxf(v, logits[4 * g + 2]);
      v = fmaxf(v, logits[4 * g + 3]);
      gm[g] = v;
    }
    unsigned gkeep = 0;
    for (int it = 0; it < 4; ++it) {
      float best = -3.4e38f; int bg = 0;
#pragma unroll
      for (int g = 0; g < 8; ++g) {
        bool ok = !((gkeep >> g) & 1u);
        if (ok && gm[g] > best) { best = gm[g]; bg = g; }
      }
      gkeep |= 1u << bg;
    }
    unsigned allow = 0;
#pragma unroll
    for (int g = 0; g < 8; ++g)
      if ((gkeep >> g) & 1u) allow |= 0xFu << (4 * g);
    unsigned taken = 0;
    float wsum = 0.f;
    int ids[4]; float wv[4];
    for (int sIt = 0; sIt < 4; ++sIt) {
      float best = -3.4e38f; int be = 0;
#pragma unroll
      for (int i = 0; i < 32; ++i) {
        bool ok = ((allow >> i) & 1u) && !((taken >> i) & 1u);
        float v = logits[i];
        if (ok && v > best) { best = v; be = i; }
      }
      taken |= 1u << be;
      ids[sIt] = be;
      float wq = expf(logits[be] - m) / sum;
      wv[sIt] = wq;
      wsum += wq;
    }
    float inv = 1.f / (wsum + 1e-9f);
#pragma unroll
    for (int sIt = 0; sIt < 4; ++sIt) {
      gidx[t * 4 + sIt] = ids[sIt];
      gw[t * 4 + sIt] = wv[sIt] * inv;
    }
  }
}

// ---------------- init dispatch buffers ----------------
__global__ __launch_bounds__(256) void initbuf_kernel(int* __restrict__ bt, float* __restrict__ bw) {
  int i = blockIdx.x * 256 + threadIdx.x;
  if (i < NEXP * CAP) { bt[i] = -1; bw[i] = 0.f; }
}

// ---------------- rank/dispatch: one block per expert, 1024 threads --------
__global__ __launch_bounds__(1024) void rank_kernel(const int* __restrict__ gidx,
                                                    const float* __restrict__ gw,
                                                    int* __restrict__ buf_tok,
                                                    float* __restrict__ buf_w,
                                                    int* __restrict__ cnt,
                                                    int* __restrict__ tslot) {
  const int e = blockIdx.x;
  const int tid = threadIdx.x, wid = tid >> 6, lane = tid & 63;
  __shared__ int wtot[16];
  int base = 0;
  for (int j0 = 0; j0 < NTOK * 4; j0 += 1024) {
    int j = j0 + tid;
    bool match = (gidx[j] == e);
    unsigned long long mb = __ballot(match);
    if (lane == 0) wtot[wid] = __popcll(mb);
    __syncthreads();
    int woff = 0, btot = 0;
#pragma unroll
    for (int w = 0; w < 16; ++w) {
      int c = wtot[w];
      if (w < wid) woff += c;
      btot += c;
    }
    if (match) {
      int pos = base + woff + __popcll(mb & ((1ull << lane) - 1ull));
      if (pos < CAP) {
        buf_tok[e * CAP + pos] = j >> 2;
        buf_w[e * CAP + pos] = gw[j];
        tslot[j] = e * CAP + pos;
      } else {
        tslot[j] = -1;
      }
    }
    base += btot;
    __syncthreads();
  }
  if (tid == 0) cnt[e] = (base < CAP) ? base : CAP;
}

// ============ up-proj v4: 256x128 tile, BK=32 chunks, 2-slot LDS (48KB) ====
// Occupancy-first: acc 4x4/wave (64 regs) + __launch_bounds__(512,4) =>
// <=128 unified regs/wave => 4 waves/SIMD; 48KB LDS => 2 blocks/CU. Two
// independent barrier domains per CU hide each other's vmcnt/barrier stalls.
// B panel 128 rows = B1/B3 interleaved at 16-row granularity (panel row
// 32q+s: s<16 -> B1 row nt*64+q*16+s, else B3), so silu pairing is
// wave-local: acc[m][2k]=v1, acc[m][2k+1]=v3 for the same 16 H-cols.
// Phase (per 32-col chunk): read 8 frags, stage next chunk (3 gload_lds),
// 16 MFMA, vmcnt(0), one barrier. Stage issued at phase top -> latency
// hides under MFMA. Swizzle (proven 0-conflict): slot^((row>>1)&3).
__global__ __launch_bounds__(512, 4) void up8_kernel(const u16* __restrict__ X,
                                                     const u16* __restrict__ w1t,
                                                     const u16* __restrict__ w3t,
                                                     const u16* __restrict__ sw1t,
                                                     const u16* __restrict__ sw3t,
                                                     u16* __restrict__ hs,
                                                     u16* __restrict__ he,
                                                     const int* __restrict__ btok,
                                                     const int* __restrict__ cnt) {
  extern __shared__ __align__(16) u16 lds_raw[];   // 2 slots x (A 16K + B 8K) = 48KB
  const int tid = threadIdx.x, wid = tid >> 6, lane = tid & 63;
  const int bid = blockIdx.x;
  const int xcd = bid & 7, off = bid >> 3;   // off 0..383
  bool expert;
  int mt, nt, e = 0;
  const u16 *B1, *B3;
  u16* H;
  if (off < 320) {
    expert = true;
    int id = xcd * 320 + off;
    e = id / 80;
    int r = id % 80;
    mt = r % 5;
    nt = r / 5;                                // 0..15 (64 H cols each)
    if (mt * 256 >= cnt[e]) return;
    B1 = w1t + ((size_t)e << 20);
    B3 = w3t + ((size_t)e << 20);
    H = he + (size_t)(e * CAP + mt * 256) * 1024;
  } else {
    expert = false;
    int id = xcd * 64 + (off - 320);
    mt = id % 32;
    nt = id / 32;                              // 0..15
    B1 = sw1t;
    B3 = sw3t;
    H = hs + (size_t)mt * 256 * 1024;
  }
  const int wr = wid >> 1, wc = wid & 1;       // 4M x 2N wave grid, 64x64/wave
  const int fr = lane & 15, fw = lane >> 4;

  // staging geometry: chunk rows 64B, 4 lanes/row; srow 0..127
  const int srow = tid >> 2;
  const int slot4 = tid & 3;
  const int sw = ((slot4 ^ ((srow >> 1) & 3)) << 3);  // pre-swizzled src col

  const u16* aP[2];
#pragma unroll
  for (int j = 0; j < 2; ++j) {
    int row = mt * 256 + j * 128 + srow;
    int grow;
    if (expert) {
      int t0 = btok[e * CAP + row];
      grow = (t0 < 0) ? 0 : t0;
    } else {
      grow = row;
    }
    aP[j] = X + (size_t)grow * 1024 + sw;
  }
  // B panel row srow -> interleaved B1/B3 source row
  const u16* bP;
  {
    int q = srow >> 5, s = srow & 31;
    const u16* base = (s < 16) ? B1 : B3;
    bP = base + (size_t)(nt * 64 + q * 16 + (s & 15)) * 1024 + sw;
  }

  auto stage = [&](int c) {
    u16* dA = lds_raw + (c & 1) * 12288 + wid * 512;
    const int g = c * 32;
    gload16(aP[0] + g, dA);
    gload16(aP[1] + g, dA + 4096);
    gload16(bP + g, dA + 8192);                 // B region starts at elem 8192
  };

  // frag-read base (swizzle lane-constant: (row>>1)&3 == (fr>>1)&3)
  const int swz = ((fw ^ ((fr >> 1) & 3)) << 3);
  const u16* aRd = lds_raw + (wr * 64 + fr) * 32 + swz;
  const u16* bRd = lds_raw + 8192 + (wc * 64 + fr) * 32 + swz;

  f32x4 acc[4][4] = {};

  stage(0);
  VM0;
  __builtin_amdgcn_s_barrier();

  for (int c = 0; c < 32; ++c) {
    const int off16 = (c & 1) * 12288;
    bf16x8 av[4], bv[4];
#pragma unroll
    for (int m = 0; m < 4; ++m)
      av[m] = *reinterpret_cast<const bf16x8*>(aRd + off16 + m * 512);
#pragma unroll
    for (int n = 0; n < 4; ++n)
      bv[n] = *reinterpret_cast<const bf16x8*>(bRd + off16 + n * 512);
    if (c < 31) stage(c + 1);
    __builtin_amdgcn_s_setprio(1);
#pragma unroll
    for (int m = 0; m < 4; ++m)
#pragma unroll
      for (int n = 0; n < 4; ++n)
        acc[m][n] = __builtin_amdgcn_mfma_f32_16x16x32_bf16(av[m], bv[n], acc[m][n], 0, 0, 0);
    __builtin_amdgcn_s_setprio(0);
    if (c < 31) {
      VM0;
      __builtin_amdgcn_s_barrier();
    }
  }

  // ---- epilogue: silu wave-local (no LDS exchange needed)
  const int row0 = wr * 64 + fw * 4;
  const int col0 = nt * 64 + wc * 32;
#pragma unroll
  for (int m = 0; m < 4; ++m)
#pragma unroll
    for (int k = 0; k < 2; ++k)
#pragma unroll
      for (int ri = 0; ri < 4; ++ri) {
        float v1 = acc[m][2 * k][ri];
        float v3 = acc[m][2 * k + 1][ri];
        float h = (v1 / (1.f + __expf(-v1))) * v3;
        H[(size_t)(row0 + m * 16 + ri) * 1024 + col0 + k * 16 + fr] = f2bf(h);
      }
}

// ============ down-proj v4: 256x128 tile, BK=32 chunks, 2-slot LDS =========
// Same occupancy-first skeleton as up8 v4.
__global__ __launch_bounds__(512, 4) void down8_kernel(const u16* __restrict__ hs,
                                                       const u16* __restrict__ he,
                                                       const u16* __restrict__ sB,
                                                       const u16* __restrict__ eB,
                                                       float* __restrict__ Out,
                                                       u16* __restrict__ OutB,
                                                       const float* __restrict__ bw,
                                                       const int* __restrict__ cnt) {
  extern __shared__ __align__(16) u16 lds_raw[];   // 2 slots x 24KB = 48KB
  const int tid = threadIdx.x, wid = tid >> 6, lane = tid & 63;
  const int bid = blockIdx.x;
  const int xcd = bid & 7, off = bid >> 3;   // off 0..191
  bool expert;
  int mt, nt, e = 0;
  const u16 *Asrc, *Bsrc;
  if (off < 160) {
    expert = true;
    int id = xcd * 160 + off;
    e = id / 40;
    int r = id % 40;
    mt = r % 5;
    nt = r / 5;                                // 0..7 (128 out cols each)
    if (mt * 256 >= cnt[e]) return;
    Asrc = he + (size_t)e * CAP * 1024;
    Bsrc = eB + ((size_t)e << 20);
  } else {
    expert = false;
    int id = xcd * 32 + (off - 160);
    mt = id % 32;
    nt = id / 32;                              // 0..7
    Asrc = hs;
    Bsrc = sB;
  }
  const int wr = wid >> 1, wc = wid & 1;       // 4M x 2N, 64x64/wave
  const int fr = lane & 15, fw = lane >> 4;

  const int srow = tid >> 2;
  const int slot4 = tid & 3;
  const int sw = ((slot4 ^ ((srow >> 1) & 3)) << 3);

  const u16* aP[2];
#pragma unroll
  for (int j = 0; j < 2; ++j)
    aP[j] = Asrc + (size_t)(mt * 256 + j * 128 + srow) * 1024 + sw;
  const u16* bP = Bsrc + (size_t)(nt * 128 + srow) * 1024 + sw;

  auto stage = [&](int c) {
    u16* dA = lds_raw + (c & 1) * 12288 + wid * 512;
    const int g = c * 32;
    gload16(aP[0] + g, dA);
    gload16(aP[1] + g, dA + 4096);
    gload16(bP + g, dA + 8192);
  };

  const int swz = ((fw ^ ((fr >> 1) & 3)) << 3);
  const u16* aRd = lds_raw + (wr * 64 + fr) * 32 + swz;
  const u16* bRd = lds_raw + 8192 + (wc * 64 + fr) * 32 + swz;

  f32x4 acc[4][4] = {};

  stage(0);
  VM0;
  __builtin_amdgcn_s_barrier();

  for (int c = 0; c < 32; ++c) {
    const int off16 = (c & 1) * 12288;
    bf16x8 av[4], bv[4];
#pragma unroll
    for (int m = 0; m < 4; ++m)
      av[m] = *reinterpret_cast<const bf16x8*>(aRd + off16 + m * 512);
#pragma unroll
    for (int n = 0; n < 4; ++n)
      bv[n] = *reinterpret_cast<const bf16x8*>(bRd + off16 + n * 512);
    if (c < 31) stage(c + 1);
    __builtin_amdgcn_s_setprio(1);
#pragma unroll
    for (int m = 0; m < 4; ++m)
#pragma unroll
      for (int n = 0; n < 4; ++n)
        acc[m][n] = __builtin_amdgcn_mfma_f32_16x16x32_bf16(av[m], bv[n], acc[m][n], 0, 0, 0);
    __builtin_amdgcn_s_setprio(0);
    if (c < 31) {
      VM0;
      __builtin_amdgcn_s_barrier();
    }
  }

  // ---- epilogue
  const int orow0 = mt * 256 + wr * 64 + fw * 4;
  const int ocol0 = nt * 128 + wc * 64;
  if (expert) {
#pragma unroll
    for (int m = 0; m < 4; ++m)
#pragma unroll
      for (int ri = 0; ri < 4; ++ri) {
        int row = orow0 + m * 16 + ri;
        int slot = e * CAP + (row - mt * 256) + mt * 256;  // = e*CAP + row
        float wgt = bw[e * CAP + row];
#pragma unroll
        for (int n = 0; n < 4; ++n)
          OutB[(size_t)(e * CAP + row) * 1024 + ocol0 + n * 16 + fr] = f2bf(acc[m][n][ri] * wgt);
        (void)slot;
      }
  } else {
#pragma unroll
    for (int m = 0; m < 4; ++m)
#pragma unroll
      for (int ri = 0; ri < 4; ++ri) {
        int row = orow0 + m * 16 + ri;
#pragma unroll
        for (int n = 0; n < 4; ++n)
          Out[(size_t)row * 1024 + ocol0 + n * 16 + fr] = acc[m][n][ri];
      }
  }
}

// ---------------- combine: out[t] += sum_k oe[tslot[t,k]] ----------------
__global__ __launch_bounds__(256) void combine_kernel(const u16* __restrict__ oe,
                                                      const int* __restrict__ tslot,
                                                      float* __restrict__ out) {
  const int t = blockIdx.x;
  const int c = threadIdx.x;
  int s0 = tslot[t * 4 + 0], s1 = tslot[t * 4 + 1];
  int s2 = tslot[t * 4 + 2], s3 = tslot[t * 4 + 3];
  float4 v = reinterpret_cast<float4*>(out + (size_t)t * 1024)[c];
  auto addsl = [&](int s) {
    if (s >= 0) {
      uint2 q = reinterpret_cast<const uint2*>(oe + (size_t)s * 1024)[c];
      v.x += bf2f((u16)(q.x & 0xffff));
      v.y += bf2f((u16)(q.x >> 16));
      v.z += bf2f((u16)(q.y & 0xffff));
      v.w += bf2f((u16)(q.y >> 16));
    }
  };
  addsl(s0); addsl(s1); addsl(s2); addsl(s3);
  reinterpret_cast<float4*>(out + (size_t)t * 1024)[c] = v;
}

extern "C" void kernel_launch(void* const* d_in, const int* in_sizes, int n_in,
                              void* d_out, int out_size, void* d_ws, size_t ws_size,
                              hipStream_t stream) {
  const float* x   = (const float*)d_in[0];
  const float* wg  = (const float*)d_in[1];
  const float* w1  = (const float*)d_in[2];
  const float* w2  = (const float*)d_in[3];
  const float* w3  = (const float*)d_in[4];
  const float* sw1 = (const float*)d_in[5];
  const float* sw2 = (const float*)d_in[6];
  const float* sw3 = (const float*)d_in[7];
  float* out = (float*)d_out;

  char* p = (char*)d_ws;
  auto alloc = [&](size_t bytes) {
    char* q = p;
    p += (bytes + 255) & ~(size_t)255;
    return q;
  };
  u16* xb   = (u16*)alloc((size_t)NTOK * 1024 * 2);
  u16* w1t  = (u16*)alloc((size_t)NEXP * 1024 * 1024 * 2);
  u16* w3t  = (u16*)alloc((size_t)NEXP * 1024 * 1024 * 2);
  u16* w2t  = (u16*)alloc((size_t)NEXP * 1024 * 1024 * 2);
  u16* sw1t = (u16*)alloc((size_t)1024 * 1024 * 2);
  u16* sw3t = (u16*)alloc((size_t)1024 * 1024 * 2);
  u16* sw2t = (u16*)alloc((size_t)1024 * 1024 * 2);
  u16* hs   = (u16*)alloc((size_t)NTOK * 1024 * 2);
  u16* he   = (u16*)alloc((size_t)NEXP * CAP * 1024 * 2);
  int*   gidx = (int*)alloc((size_t)NTOK * 4 * 4);
  float* gww  = (float*)alloc((size_t)NTOK * 4 * 4);
  int*   btok = (int*)alloc((size_t)NEXP * CAP * 4);
  float* bww  = (float*)alloc((size_t)NEXP * CAP * 4);
  int*   cnt  = (int*)alloc((size_t)NEXP * 4);
  int*   tslot= (int*)alloc((size_t)NTOK * 4 * 4);
  // slot-output buffer overlays w1t/w3t (dead after up8_kernel):
  u16* oe = w1t;

  // 1. converts / transposes
  conv_x_kernel<<<NTOK * 1024 / 1024, 256, 0, stream>>>(x, xb);
  tconv_all_kernel<<<dim3(32, 32, 99), 256, 0, stream>>>(w1, w3, w2, sw1, sw3, sw2,
                                                         w1t, w3t, w2t, sw1t, sw3t, sw2t);
  // 2. gating + dispatch
  gate_kernel<<<NTOK, 256, 0, stream>>>(x, wg, gidx, gww);
  initbuf_kernel<<<(NEXP * CAP + 255) / 256, 256, 0, stream>>>(btok, bww);
  rank_kernel<<<NEXP, 1024, 0, stream>>>(gidx, gww, btok, bww, cnt, tslot);
  // 3. up (256x128 tile, 48KB LDS, 2 blocks/CU, 4 waves/SIMD)
  up8_kernel<<<3072, 512, 49152, stream>>>(xb, w1t, w3t, sw1t, sw3t, hs, he, btok, cnt);
  // 4. down (256x128 tile, 48KB LDS, 2 blocks/CU)
  down8_kernel<<<1536, 512, 49152, stream>>>(hs, he, sw2t, w2t, out, oe, bww, cnt);
  // 5. gather-combine expert contributions into out
  combine_kernel<<<NTOK, 256, 0, stream>>>(oe, tslot, out);
}

// Round 4
// 567.405 us; speedup vs baseline: 1.0455x; 1.0191x over previous
//
#include <hip/hip_runtime.h>
#include <stdint.h>

#define NTOK 8192
#define CAP  1280
#define NEXP 32

typedef __bf16 bf16x8 __attribute__((ext_vector_type(8)));
typedef float f32x4 __attribute__((ext_vector_type(4)));
typedef unsigned short u16;

__device__ __forceinline__ u16 f2bf(float f) {
  unsigned u = __builtin_bit_cast(unsigned, f);
  u = (u + 0x7fffu + ((u >> 16) & 1u)) >> 16;
  return (u16)u;
}
__device__ __forceinline__ float bf2f(u16 h) {
  return __builtin_bit_cast(float, ((unsigned)h) << 16);
}

__device__ __forceinline__ void gload16(const void* g, void* l) {
  __builtin_amdgcn_global_load_lds(
      (const __attribute__((address_space(1))) void*)g,
      (__attribute__((address_space(3))) void*)l, 16, 0, 0);
}

#define VM3 asm volatile("s_waitcnt vmcnt(3)" ::: "memory")
#define VM0 asm volatile("s_waitcnt vmcnt(0)" ::: "memory")

// ---------------- convert x (fp32 -> bf16), 4 elems/thread ----------------
__global__ __launch_bounds__(256) void conv_x_kernel(const float* __restrict__ in,
                                                     u16* __restrict__ out) {
  int i = blockIdx.x * 256 + threadIdx.x;
  float4 v = reinterpret_cast<const float4*>(in)[i];
  uint2 o;
  o.x = (unsigned)f2bf(v.x) | ((unsigned)f2bf(v.y) << 16);
  o.y = (unsigned)f2bf(v.z) | ((unsigned)f2bf(v.w) << 16);
  reinterpret_cast<uint2*>(out)[i] = o;
}

// -------- transpose+convert 1024x1024 fp32 -> bf16, all weights in one ----
__global__ __launch_bounds__(256) void tconv_all_kernel(
    const float* __restrict__ w1, const float* __restrict__ w3,
    const float* __restrict__ w2, const float* __restrict__ sw1,
    const float* __restrict__ sw3, const float* __restrict__ sw2,
    u16* __restrict__ w1t, u16* __restrict__ w3t, u16* __restrict__ w2t,
    u16* __restrict__ sw1t, u16* __restrict__ sw3t, u16* __restrict__ sw2t) {
  __shared__ float tile[32][33];
  const int z = blockIdx.z;
  const float* src;
  u16* dst;
  if (z < 32)      { src = w1 + (size_t)z * 1048576;        dst = w1t + (size_t)z * 1048576; }
  else if (z < 64) { src = w3 + (size_t)(z - 32) * 1048576; dst = w3t + (size_t)(z - 32) * 1048576; }
  else if (z < 96) { src = w2 + (size_t)(z - 64) * 1048576; dst = w2t + (size_t)(z - 64) * 1048576; }
  else if (z == 96){ src = sw1; dst = sw1t; }
  else if (z == 97){ src = sw3; dst = sw3t; }
  else             { src = sw2; dst = sw2t; }
  int r0 = blockIdx.x * 32, c0 = blockIdx.y * 32;
  int tid = threadIdx.x;
#pragma unroll
  for (int i = 0; i < 4; ++i) {
    int t = tid + i * 256, r = t >> 5, c = t & 31;
    tile[r][c] = src[(size_t)(r0 + r) * 1024 + (c0 + c)];
  }
  __syncthreads();
#pragma unroll
  for (int i = 0; i < 4; ++i) {
    int t = tid + i * 256, cc = t >> 5, rr = t & 31;
    dst[(size_t)(c0 + cc) * 1024 + (r0 + rr)] = f2bf(tile[rr][cc]);
  }
}

// ---------------- gating: one block per token ----------------
__global__ __launch_bounds__(256) void gate_kernel(const float* __restrict__ x,
                                                   const float* __restrict__ wg,
                                                   int* __restrict__ gidx,
                                                   float* __restrict__ gw) {
  const int t = blockIdx.x;
  __shared__ float xl[1024];
  __shared__ float logits[32];
  const int tid = threadIdx.x;
  reinterpret_cast<float4*>(xl)[tid] = reinterpret_cast<const float4*>(x + (size_t)t * 1024)[tid];
  __syncthreads();
  const int e = tid >> 3, p = tid & 7;
  const float4* wrow = reinterpret_cast<const float4*>(wg + (size_t)e * 1024);
  const float4* xv4 = reinterpret_cast<const float4*>(xl);
  float s = 0.f;
#pragma unroll
  for (int i = 0; i < 32; ++i) {
    int c = p + 8 * i;
    float4 xv = xv4[c];
    float4 wv = wrow[c];
    s += xv.x * wv.x + xv.y * wv.y + xv.z * wv.z + xv.w * wv.w;
  }
  s += __shfl_xor(s, 1);
  s += __shfl_xor(s, 2);
  s += __shfl_xor(s, 4);
  if (p == 0) logits[e] = s;
  __syncthreads();
  if (tid == 0) {
    float m = logits[0];
#pragma unroll
    for (int i = 1; i < 32; ++i) m = fmaxf(m, logits[i]);
    float sum = 0.f;
#pragma unroll
    for (int i = 0; i < 32; ++i) sum += expf(logits[i] - m);
    float gm[8];
#pragma unroll
    for (int g = 0; g < 8; ++g) {
      float v = logits[4 * g];
      v = fmaxf(v, logits[4 * g + 1]);
      v = fmaxf(v, logits[4 * g + 2]);
      v = fmaxf(v, logits[4 * g + 3]);
      gm[g] = v;
    }
    unsigned gkeep = 0;
    for (int it = 0; it < 4; ++it) {
      float best = -3.4e38f; int bg = 0;
#pragma unroll
      for (int g = 0; g < 8; ++g) {
        bool ok = !((gkeep >> g) & 1u);
        if (ok && gm[g] > best) { best = gm[g]; bg = g; }
      }
      gkeep |= 1u << bg;
    }
    unsigned allow = 0;
#pragma unroll
    for (int g = 0; g < 8; ++g)
      if ((gkeep >> g) & 1u) allow |= 0xFu << (4 * g);
    unsigned taken = 0;
    float wsum = 0.f;
    int ids[4]; float wv[4];
    for (int sIt = 0; sIt < 4; ++sIt) {
      float best = -3.4e38f; int be = 0;
#pragma unroll
      for (int i = 0; i < 32; ++i) {
        bool ok = ((allow >> i) & 1u) && !((taken >> i) & 1u);
        float v = logits[i];
        if (ok && v > best) { best = v; be = i; }
      }
      taken |= 1u << be;
      ids[sIt] = be;
      float wq = expf(logits[be] - m) / sum;
      wv[sIt] = wq;
      wsum += wq;
    }
    float inv = 1.f / (wsum + 1e-9f);
#pragma unroll
    for (int sIt = 0; sIt < 4; ++sIt) {
      gidx[t * 4 + sIt] = ids[sIt];
      gw[t * 4 + sIt] = wv[sIt] * inv;
    }
  }
}

// ---------------- init dispatch buffers ----------------
__global__ __launch_bounds__(256) void initbuf_kernel(int* __restrict__ bt, float* __restrict__ bw) {
  int i = blockIdx.x * 256 + threadIdx.x;
  if (i < NEXP * CAP) { bt[i] = -1; bw[i] = 0.f; }
}

// ---------------- rank/dispatch: one block per expert, 1024 threads --------
__global__ __launch_bounds__(1024) void rank_kernel(const int* __restrict__ gidx,
                                                    const float* __restrict__ gw,
                                                    int* __restrict__ buf_tok,
                                                    float* __restrict__ buf_w,
                                                    int* __restrict__ cnt,
                                                    int* __restrict__ tslot) {
  const int e = blockIdx.x;
  const int tid = threadIdx.x, wid = tid >> 6, lane = tid & 63;
  __shared__ int wtot[16];
  int base = 0;
  for (int j0 = 0; j0 < NTOK * 4; j0 += 1024) {
    int j = j0 + tid;
    bool match = (gidx[j] == e);
    unsigned long long mb = __ballot(match);
    if (lane == 0) wtot[wid] = __popcll(mb);
    __syncthreads();
    int woff = 0, btot = 0;
#pragma unroll
    for (int w = 0; w < 16; ++w) {
      int c = wtot[w];
      if (w < wid) woff += c;
      btot += c;
    }
    if (match) {
      int pos = base + woff + __popcll(mb & ((1ull << lane) - 1ull));
      if (pos < CAP) {
        buf_tok[e * CAP + pos] = j >> 2;
        buf_w[e * CAP + pos] = gw[j];
        tslot[j] = e * CAP + pos;
      } else {
        tslot[j] = -1;
      }
    }
    base += btot;
    __syncthreads();
  }
  if (tid == 0) cnt[e] = (base < CAP) ? base : CAP;
}

// ============ up-proj v5: 256x128 tile, BK=32, 3-slot ring, depth-2 =========
// v4 occupancy (2 blocks/CU, 4 waves/SIMD) + T4 counted vmcnt: 3 LDS slots
// (3 x 24KB = 72KB; 2 blocks x 72 = 144 <= 160KB, regs remain the cap).
// Phase c: read frags(slot c%3), stage chunk c+2 (slot (c+2)%3), 16 MFMA,
// vmcnt(3) (chunk c+1 landed, c+2 in flight), barrier. A load gets a full
// phase (+MFMA) ~2000 cyc to cover ~900 cyc HBM latency, vs 310 in v4.
// Slot safety: 1 barrier/phase => wave skew <= 1 phase; write slot (c+2)%3
// != read slot c%3 (3 does not divide 2). Swizzle proven 0-conflict.
__global__ __launch_bounds__(512, 4) void up8_kernel(const u16* __restrict__ X,
                                                     const u16* __restrict__ w1t,
                                                     const u16* __restrict__ w3t,
                                                     const u16* __restrict__ sw1t,
                                                     const u16* __restrict__ sw3t,
                                                     u16* __restrict__ hs,
                                                     u16* __restrict__ he,
                                                     const int* __restrict__ btok,
                                                     const int* __restrict__ cnt) {
  extern __shared__ __align__(16) u16 lds_raw[];   // 3 slots x (A 16K + B 8K) = 72KB
  const int tid = threadIdx.x, wid = tid >> 6, lane = tid & 63;
  const int bid = blockIdx.x;
  const int xcd = bid & 7, off = bid >> 3;   // off 0..383
  bool expert;
  int mt, nt, e = 0;
  const u16 *B1, *B3;
  u16* H;
  if (off < 320) {
    expert = true;
    int id = xcd * 320 + off;
    e = id / 80;
    int r = id % 80;
    mt = r % 5;
    nt = r / 5;                                // 0..15 (64 H cols each)
    if (mt * 256 >= cnt[e]) return;
    B1 = w1t + ((size_t)e << 20);
    B3 = w3t + ((size_t)e << 20);
    H = he + (size_t)(e * CAP + mt * 256) * 1024;
  } else {
    expert = false;
    int id = xcd * 64 + (off - 320);
    mt = id % 32;
    nt = id / 32;                              // 0..15
    B1 = sw1t;
    B3 = sw3t;
    H = hs + (size_t)mt * 256 * 1024;
  }
  const int wr = wid >> 1, wc = wid & 1;       // 4M x 2N wave grid, 64x64/wave
  const int fr = lane & 15, fw = lane >> 4;

  // staging geometry: chunk rows 64B, 4 lanes/row; srow 0..127
  const int srow = tid >> 2;
  const int slot4 = tid & 3;
  const int sw = ((slot4 ^ ((srow >> 1) & 3)) << 3);  // pre-swizzled src col

  const u16* aP[2];
#pragma unroll
  for (int j = 0; j < 2; ++j) {
    int row = mt * 256 + j * 128 + srow;
    int grow;
    if (expert) {
      int t0 = btok[e * CAP + row];
      grow = (t0 < 0) ? 0 : t0;
    } else {
      grow = row;
    }
    aP[j] = X + (size_t)grow * 1024 + sw;
  }
  // B panel row srow -> interleaved B1/B3 source row
  const u16* bP;
  {
    int q = srow >> 5, s = srow & 31;
    const u16* base = (s < 16) ? B1 : B3;
    bP = base + (size_t)(nt * 64 + q * 16 + (s & 15)) * 1024 + sw;
  }

  auto stage = [&](int c, int sl) {
    u16* dA = lds_raw + sl * 12288 + wid * 512;
    const int g = c * 32;
    gload16(aP[0] + g, dA);
    gload16(aP[1] + g, dA + 4096);
    gload16(bP + g, dA + 8192);                 // B region at elem 8192
  };

  // frag-read base (swizzle lane-constant: (row>>1)&3 == (fr>>1)&3)
  const int swz = ((fw ^ ((fr >> 1) & 3)) << 3);
  const u16* aRd = lds_raw + (wr * 64 + fr) * 32 + swz;
  const u16* bRd = lds_raw + 8192 + (wc * 64 + fr) * 32 + swz;

  f32x4 acc[4][4] = {};

  stage(0, 0);
  stage(1, 1);
  VM3;                                          // chunk 0 landed, 1 in flight
  __builtin_amdgcn_s_barrier();

  int sl = 0, slw = 2;
  for (int c = 0; c < 32; ++c) {
    const int offL = sl * 12288;
    bf16x8 av[4], bv[4];
#pragma unroll
    for (int m = 0; m < 4; ++m)
      av[m] = *reinterpret_cast<const bf16x8*>(aRd + offL + m * 512);
#pragma unroll
    for (int n = 0; n < 4; ++n)
      bv[n] = *reinterpret_cast<const bf16x8*>(bRd + offL + n * 512);
    if (c < 30) stage(c + 2, slw);
    __builtin_amdgcn_s_setprio(1);
#pragma unroll
    for (int m = 0; m < 4; ++m)
#pragma unroll
      for (int n = 0; n < 4; ++n)
        acc[m][n] = __builtin_amdgcn_mfma_f32_16x16x32_bf16(av[m], bv[n], acc[m][n], 0, 0, 0);
    __builtin_amdgcn_s_setprio(0);
    if (c < 30) {
      VM3;                                      // chunk c+1 landed
      __builtin_amdgcn_s_barrier();
    } else if (c == 30) {
      VM0;                                      // chunk 31 landed
      __builtin_amdgcn_s_barrier();
    }
    sl = (sl == 2) ? 0 : sl + 1;
    slw = (slw == 2) ? 0 : slw + 1;
  }

  // ---- epilogue: silu wave-local
  const int row0 = wr * 64 + fw * 4;
  const int col0 = nt * 64 + wc * 32;
#pragma unroll
  for (int m = 0; m < 4; ++m)
#pragma unroll
    for (int k = 0; k < 2; ++k)
#pragma unroll
      for (int ri = 0; ri < 4; ++ri) {
        float v1 = acc[m][2 * k][ri];
        float v3 = acc[m][2 * k + 1][ri];
        float h = (v1 / (1.f + __expf(-v1))) * v3;
        H[(size_t)(row0 + m * 16 + ri) * 1024 + col0 + k * 16 + fr] = f2bf(h);
      }
}

// ============ down-proj v5: 256x128 tile, BK=32, 3-slot ring, depth-2 ======
__global__ __launch_bounds__(512, 4) void down8_kernel(const u16* __restrict__ hs,
                                                       const u16* __restrict__ he,
                                                       const u16* __restrict__ sB,
                                                       const u16* __restrict__ eB,
                                                       float* __restrict__ Out,
                                                       u16* __restrict__ OutB,
                                                       const float* __restrict__ bw,
                                                       const int* __restrict__ cnt) {
  extern __shared__ __align__(16) u16 lds_raw[];   // 3 slots x 24KB = 72KB
  const int tid = threadIdx.x, wid = tid >> 6, lane = tid & 63;
  const int bid = blockIdx.x;
  const int xcd = bid & 7, off = bid >> 3;   // off 0..191
  bool expert;
  int mt, nt, e = 0;
  const u16 *Asrc, *Bsrc;
  if (off < 160) {
    expert = true;
    int id = xcd * 160 + off;
    e = id / 40;
    int r = id % 40;
    mt = r % 5;
    nt = r / 5;                                // 0..7 (128 out cols each)
    if (mt * 256 >= cnt[e]) return;
    Asrc = he + (size_t)e * CAP * 1024;
    Bsrc = eB + ((size_t)e << 20);
  } else {
    expert = false;
    int id = xcd * 32 + (off - 160);
    mt = id % 32;
    nt = id / 32;                              // 0..7
    Asrc = hs;
    Bsrc = sB;
  }
  const int wr = wid >> 1, wc = wid & 1;       // 4M x 2N, 64x64/wave
  const int fr = lane & 15, fw = lane >> 4;

  const int srow = tid >> 2;
  const int slot4 = tid & 3;
  const int sw = ((slot4 ^ ((srow >> 1) & 3)) << 3);

  const u16* aP[2];
#pragma unroll
  for (int j = 0; j < 2; ++j)
    aP[j] = Asrc + (size_t)(mt * 256 + j * 128 + srow) * 1024 + sw;
  const u16* bP = Bsrc + (size_t)(nt * 128 + srow) * 1024 + sw;

  auto stage = [&](int c, int sl) {
    u16* dA = lds_raw + sl * 12288 + wid * 512;
    const int g = c * 32;
    gload16(aP[0] + g, dA);
    gload16(aP[1] + g, dA + 4096);
    gload16(bP + g, dA + 8192);
  };

  const int swz = ((fw ^ ((fr >> 1) & 3)) << 3);
  const u16* aRd = lds_raw + (wr * 64 + fr) * 32 + swz;
  const u16* bRd = lds_raw + 8192 + (wc * 64 + fr) * 32 + swz;

  f32x4 acc[4][4] = {};

  stage(0, 0);
  stage(1, 1);
  VM3;
  __builtin_amdgcn_s_barrier();

  int sl = 0, slw = 2;
  for (int c = 0; c < 32; ++c) {
    const int offL = sl * 12288;
    bf16x8 av[4], bv[4];
#pragma unroll
    for (int m = 0; m < 4; ++m)
      av[m] = *reinterpret_cast<const bf16x8*>(aRd + offL + m * 512);
#pragma unroll
    for (int n = 0; n < 4; ++n)
      bv[n] = *reinterpret_cast<const bf16x8*>(bRd + offL + n * 512);
    if (c < 30) stage(c + 2, slw);
    __builtin_amdgcn_s_setprio(1);
#pragma unroll
    for (int m = 0; m < 4; ++m)
#pragma unroll
      for (int n = 0; n < 4; ++n)
        acc[m][n] = __builtin_amdgcn_mfma_f32_16x16x32_bf16(av[m], bv[n], acc[m][n], 0, 0, 0);
    __builtin_amdgcn_s_setprio(0);
    if (c < 30) {
      VM3;
      __builtin_amdgcn_s_barrier();
    } else if (c == 30) {
      VM0;
      __builtin_amdgcn_s_barrier();
    }
    sl = (sl == 2) ? 0 : sl + 1;
    slw = (slw == 2) ? 0 : slw + 1;
  }

  // ---- epilogue
  const int orow0 = mt * 256 + wr * 64 + fw * 4;
  const int ocol0 = nt * 128 + wc * 64;
  if (expert) {
#pragma unroll
    for (int m = 0; m < 4; ++m)
#pragma unroll
      for (int ri = 0; ri < 4; ++ri) {
        int row = orow0 + m * 16 + ri;
        float wgt = bw[e * CAP + row];
#pragma unroll
        for (int n = 0; n < 4; ++n)
          OutB[(size_t)(e * CAP + row) * 1024 + ocol0 + n * 16 + fr] = f2bf(acc[m][n][ri] * wgt);
      }
  } else {
#pragma unroll
    for (int m = 0; m < 4; ++m)
#pragma unroll
      for (int ri = 0; ri < 4; ++ri) {
        int row = orow0 + m * 16 + ri;
#pragma unroll
        for (int n = 0; n < 4; ++n)
          Out[(size_t)row * 1024 + ocol0 + n * 16 + fr] = acc[m][n][ri];
      }
  }
}

// ---------------- combine: out[t] += sum_k oe[tslot[t,k]] ----------------
__global__ __launch_bounds__(256) void combine_kernel(const u16* __restrict__ oe,
                                                      const int* __restrict__ tslot,
                                                      float* __restrict__ out) {
  const int t = blockIdx.x;
  const int c = threadIdx.x;
  int s0 = tslot[t * 4 + 0], s1 = tslot[t * 4 + 1];
  int s2 = tslot[t * 4 + 2], s3 = tslot[t * 4 + 3];
  float4 v = reinterpret_cast<float4*>(out + (size_t)t * 1024)[c];
  auto addsl = [&](int s) {
    if (s >= 0) {
      uint2 q = reinterpret_cast<const uint2*>(oe + (size_t)s * 1024)[c];
      v.x += bf2f((u16)(q.x & 0xffff));
      v.y += bf2f((u16)(q.x >> 16));
      v.z += bf2f((u16)(q.y & 0xffff));
      v.w += bf2f((u16)(q.y >> 16));
    }
  };
  addsl(s0); addsl(s1); addsl(s2); addsl(s3);
  reinterpret_cast<float4*>(out + (size_t)t * 1024)[c] = v;
}

extern "C" void kernel_launch(void* const* d_in, const int* in_sizes, int n_in,
                              void* d_out, int out_size, void* d_ws, size_t ws_size,
                              hipStream_t stream) {
  const float* x   = (const float*)d_in[0];
  const float* wg  = (const float*)d_in[1];
  const float* w1  = (const float*)d_in[2];
  const float* w2  = (const float*)d_in[3];
  const float* w3  = (const float*)d_in[4];
  const float* sw1 = (const float*)d_in[5];
  const float* sw2 = (const float*)d_in[6];
  const float* sw3 = (const float*)d_in[7];
  float* out = (float*)d_out;

  char* p = (char*)d_ws;
  auto alloc = [&](size_t bytes) {
    char* q = p;
    p += (bytes + 255) & ~(size_t)255;
    return q;
  };
  u16* xb   = (u16*)alloc((size_t)NTOK * 1024 * 2);
  u16* w1t  = (u16*)alloc((size_t)NEXP * 1024 * 1024 * 2);
  u16* w3t  = (u16*)alloc((size_t)NEXP * 1024 * 1024 * 2);
  u16* w2t  = (u16*)alloc((size_t)NEXP * 1024 * 1024 * 2);
  u16* sw1t = (u16*)alloc((size_t)1024 * 1024 * 2);
  u16* sw3t = (u16*)alloc((size_t)1024 * 1024 * 2);
  u16* sw2t = (u16*)alloc((size_t)1024 * 1024 * 2);
  u16* hs   = (u16*)alloc((size_t)NTOK * 1024 * 2);
  u16* he   = (u16*)alloc((size_t)NEXP * CAP * 1024 * 2);
  int*   gidx = (int*)alloc((size_t)NTOK * 4 * 4);
  float* gww  = (float*)alloc((size_t)NTOK * 4 * 4);
  int*   btok = (int*)alloc((size_t)NEXP * CAP * 4);
  float* bww  = (float*)alloc((size_t)NEXP * CAP * 4);
  int*   cnt  = (int*)alloc((size_t)NEXP * 4);
  int*   tslot= (int*)alloc((size_t)NTOK * 4 * 4);
  // slot-output buffer overlays w1t/w3t (dead after up8_kernel):
  u16* oe = w1t;

  // 1. converts / transposes
  conv_x_kernel<<<NTOK * 1024 / 1024, 256, 0, stream>>>(x, xb);
  tconv_all_kernel<<<dim3(32, 32, 99), 256, 0, stream>>>(w1, w3, w2, sw1, sw3, sw2,
                                                         w1t, w3t, w2t, sw1t, sw3t, sw2t);
  // 2. gating + dispatch
  gate_kernel<<<NTOK, 256, 0, stream>>>(x, wg, gidx, gww);
  initbuf_kernel<<<(NEXP * CAP + 255) / 256, 256, 0, stream>>>(btok, bww);
  rank_kernel<<<NEXP, 1024, 0, stream>>>(gidx, gww, btok, bww, cnt, tslot);
  // 3. up (256x128 tile, 72KB LDS 3-slot ring, 2 blocks/CU, 4 waves/SIMD)
  up8_kernel<<<3072, 512, 73728, stream>>>(xb, w1t, w3t, sw1t, sw3t, hs, he, btok, cnt);
  // 4. down (256x128 tile, 72KB LDS 3-slot ring, 2 blocks/CU)
  down8_kernel<<<1536, 512, 73728, stream>>>(hs, he, sw2t, w2t, out, oe, bww, cnt);
  // 5. gather-combine expert contributions into out
  combine_kernel<<<NTOK, 256, 0, stream>>>(oe, tslot, out);
}